// Round 1
// baseline (21844.662 us; speedup 1.0000x reference)
//
#include <hip/hip_runtime.h>
#include <cstdint>

#define DEVFN static __device__ __forceinline__

// ============================================================================
// conv3 (dilated, relu applied to input, optional out = alpha*src + conv + b)
// Tile: 64 co x 128 t per block, 256 threads, thread = 4co x 8t (t stride 16)
// ============================================================================
__global__ __launch_bounds__(256)
void conv3_k(const float* __restrict__ in, const float* __restrict__ w,
             const float* __restrict__ bias, const float* __restrict__ src,
             float* __restrict__ out, int L, int d, float alpha)
{
    __shared__ float xs[16][292];      // 16 ci x (128 + 2*81 = 290) max
    __shared__ float wsm[16 * 3 * 64]; // [ci][k][co]
    const int tid  = threadIdx.x;
    const int t0   = blockIdx.x * 128;
    const int co0  = blockIdx.y * 64;
    const int b    = blockIdx.z;
    const int span = 128 + 2 * d;
    const float* inb = in + (size_t)b * 256 * L;
    const int t_g  = tid & 15;
    const int co_g = tid >> 4;

    float acc[4][8];
#pragma unroll
    for (int j = 0; j < 4; ++j)
#pragma unroll
        for (int it = 0; it < 8; ++it) acc[j][it] = 0.f;

    for (int cc = 0; cc < 16; ++cc) {
        const int ci0 = cc * 16;
        {   // stage x tile (with relu) : row ci_l loaded by 16 lanes
            const int ci_l = tid >> 4;
            const int lane = tid & 15;
            const float* row = inb + (size_t)(ci0 + ci_l) * L;
            for (int tt = lane; tt < span; tt += 16) {
                int t = t0 - d + tt;
                float v = (t >= 0 && t < L) ? row[t] : 0.f;
                xs[ci_l][tt] = fmaxf(v, 0.f);
            }
        }
        // stage weights: wsm[(ci*3+k)*64 + co]
        for (int idx = tid; idx < 16 * 3 * 64; idx += 256) {
            int co_l = idx & 63;
            int rest = idx >> 6;           // = ci_l*3 + k
            int k = rest % 3, ci_l = rest / 3;
            wsm[idx] = w[((size_t)(co0 + co_l) * 256 + (ci0 + ci_l)) * 3 + k];
        }
        __syncthreads();
#pragma unroll 4
        for (int ci_l = 0; ci_l < 16; ++ci_l) {
#pragma unroll
            for (int k = 0; k < 3; ++k) {
                const float4 wv = *(const float4*)&wsm[(ci_l * 3 + k) * 64 + co_g * 4];
                const int base = t_g + k * d;
#pragma unroll
                for (int it = 0; it < 8; ++it) {
                    const float xv = xs[ci_l][base + 16 * it];
                    acc[0][it] = fmaf(wv.x, xv, acc[0][it]);
                    acc[1][it] = fmaf(wv.y, xv, acc[1][it]);
                    acc[2][it] = fmaf(wv.z, xv, acc[2][it]);
                    acc[3][it] = fmaf(wv.w, xv, acc[3][it]);
                }
            }
        }
        __syncthreads();
    }
#pragma unroll
    for (int j = 0; j < 4; ++j) {
        const int co = co0 + co_g * 4 + j;
        const float bv = bias[co];
        float* orow = out + ((size_t)b * 256 + co) * L;
        const float* srow = src + ((size_t)b * 256 + co) * L;
#pragma unroll
        for (int it = 0; it < 8; ++it) {
            const int t = t0 + t_g + 16 * it;
            float v = acc[j][it] + bv;
            if (alpha != 0.f) v += alpha * srow[t];
            orow[t] = v;
        }
    }
}

// ============================================================================
// strided conv k=4 s=2 p=1, 256->256, no input activation
// ============================================================================
__global__ __launch_bounds__(256)
void conv4s2_k(const float* __restrict__ in, const float* __restrict__ w,
               const float* __restrict__ bias, float* __restrict__ out, int Lout)
{
    __shared__ float xs[16][260];      // span 258
    __shared__ float wsm[16 * 4 * 64]; // [ci][k][co]
    const int Lin = Lout * 2;
    const int tid  = threadIdx.x;
    const int t0   = blockIdx.x * 128;
    const int co0  = blockIdx.y * 64;
    const int b    = blockIdx.z;
    const float* inb = in + (size_t)b * 256 * Lin;
    const int t_g  = tid & 15;
    const int co_g = tid >> 4;

    float acc[4][8];
#pragma unroll
    for (int j = 0; j < 4; ++j)
#pragma unroll
        for (int it = 0; it < 8; ++it) acc[j][it] = 0.f;

    for (int cc = 0; cc < 16; ++cc) {
        const int ci0 = cc * 16;
        {
            const int ci_l = tid >> 4;
            const int lane = tid & 15;
            const float* row = inb + (size_t)(ci0 + ci_l) * Lin;
            for (int tt = lane; tt < 258; tt += 16) {
                int t = 2 * t0 - 1 + tt;
                xs[ci_l][tt] = (t >= 0 && t < Lin) ? row[t] : 0.f;
            }
        }
        for (int idx = tid; idx < 16 * 4 * 64; idx += 256) {
            int co_l = idx & 63;
            int rest = idx >> 6;          // = ci_l*4 + k
            int k = rest & 3, ci_l = rest >> 2;
            wsm[idx] = w[((size_t)(co0 + co_l) * 256 + (ci0 + ci_l)) * 4 + k];
        }
        __syncthreads();
#pragma unroll 4
        for (int ci_l = 0; ci_l < 16; ++ci_l) {
#pragma unroll
            for (int k = 0; k < 4; ++k) {
                const float4 wv = *(const float4*)&wsm[(ci_l * 4 + k) * 64 + co_g * 4];
#pragma unroll
                for (int it = 0; it < 8; ++it) {
                    const float xv = xs[ci_l][2 * t_g + 32 * it + k];
                    acc[0][it] = fmaf(wv.x, xv, acc[0][it]);
                    acc[1][it] = fmaf(wv.y, xv, acc[1][it]);
                    acc[2][it] = fmaf(wv.z, xv, acc[2][it]);
                    acc[3][it] = fmaf(wv.w, xv, acc[3][it]);
                }
            }
        }
        __syncthreads();
    }
#pragma unroll
    for (int j = 0; j < 4; ++j) {
        const int co = co0 + co_g * 4 + j;
        const float bv = bias[co];
        float* orow = out + ((size_t)b * 256 + co) * Lout;
#pragma unroll
        for (int it = 0; it < 8; ++it)
            orow[t0 + t_g + 16 * it] = acc[j][it] + bv;
    }
}

// ============================================================================
// conv transpose k=4 s=2 p=1, 256->256.  out[2m]=x[m]w1+x[m-1]w3 ;
// out[2m+1]=x[m+1]w0+x[m]w2.  Tile 64co x 64m, thread 4co x 4m.
// ============================================================================
__global__ __launch_bounds__(256)
void convT_k(const float* __restrict__ in, const float* __restrict__ w,
             const float* __restrict__ bias, float* __restrict__ out, int Lin)
{
    __shared__ float xs[16][68];       // span 66
    __shared__ float wsm[16 * 4 * 64]; // [ci][k][co]
    const int Lout = Lin * 2;
    const int tid  = threadIdx.x;
    const int m0   = blockIdx.x * 64;
    const int co0  = blockIdx.y * 64;
    const int b    = blockIdx.z;
    const float* inb = in + (size_t)b * 256 * Lin;
    const int m_g  = tid & 15;
    const int co_g = tid >> 4;

    float accE[4][4], accO[4][4];
#pragma unroll
    for (int j = 0; j < 4; ++j)
#pragma unroll
        for (int im = 0; im < 4; ++im) { accE[j][im] = 0.f; accO[j][im] = 0.f; }

    for (int cc = 0; cc < 16; ++cc) {
        const int ci0 = cc * 16;
        {
            const int ci_l = tid >> 4;
            const int lane = tid & 15;
            const float* row = inb + (size_t)(ci0 + ci_l) * Lin;
            for (int tt = lane; tt < 66; tt += 16) {
                int t = m0 - 1 + tt;
                xs[ci_l][tt] = (t >= 0 && t < Lin) ? row[t] : 0.f;
            }
        }
        for (int idx = tid; idx < 16 * 4 * 64; idx += 256) {
            int co_l = idx & 63;
            int rest = idx >> 6;          // = ci_l*4 + k
            int k = rest & 3, ci_l = rest >> 2;
            // w layout: [in][out][k]
            wsm[idx] = w[((size_t)(ci0 + ci_l) * 256 + (co0 + co_l)) * 4 + k];
        }
        __syncthreads();
#pragma unroll 4
        for (int ci_l = 0; ci_l < 16; ++ci_l) {
            const float4 w0v = *(const float4*)&wsm[(ci_l * 4 + 0) * 64 + co_g * 4];
            const float4 w1v = *(const float4*)&wsm[(ci_l * 4 + 1) * 64 + co_g * 4];
            const float4 w2v = *(const float4*)&wsm[(ci_l * 4 + 2) * 64 + co_g * 4];
            const float4 w3v = *(const float4*)&wsm[(ci_l * 4 + 3) * 64 + co_g * 4];
#pragma unroll
            for (int im = 0; im < 4; ++im) {
                const int mi = m_g + 16 * im;
                const float xm1 = xs[ci_l][mi];
                const float x0  = xs[ci_l][mi + 1];
                const float xp1 = xs[ci_l][mi + 2];
                accE[0][im] = fmaf(w1v.x, x0, fmaf(w3v.x, xm1, accE[0][im]));
                accE[1][im] = fmaf(w1v.y, x0, fmaf(w3v.y, xm1, accE[1][im]));
                accE[2][im] = fmaf(w1v.z, x0, fmaf(w3v.z, xm1, accE[2][im]));
                accE[3][im] = fmaf(w1v.w, x0, fmaf(w3v.w, xm1, accE[3][im]));
                accO[0][im] = fmaf(w0v.x, xp1, fmaf(w2v.x, x0, accO[0][im]));
                accO[1][im] = fmaf(w0v.y, xp1, fmaf(w2v.y, x0, accO[1][im]));
                accO[2][im] = fmaf(w0v.z, xp1, fmaf(w2v.z, x0, accO[2][im]));
                accO[3][im] = fmaf(w0v.w, xp1, fmaf(w2v.w, x0, accO[3][im]));
            }
        }
        __syncthreads();
    }
#pragma unroll
    for (int j = 0; j < 4; ++j) {
        const int co = co0 + co_g * 4 + j;
        const float bv = bias[co];
        float* orow = out + ((size_t)b * 256 + co) * Lout;
#pragma unroll
        for (int im = 0; im < 4; ++im) {
            const int t = 2 * (m0 + m_g + 16 * im);
            float2 v = make_float2(accE[j][im] + bv, accO[j][im] + bv);
            *(float2*)(orow + t) = v;
        }
    }
}

// ============================================================================
// first conv: 1->256 ch, k=4 s=2 p=1
// ============================================================================
__global__ __launch_bounds__(256)
void down0_k(const float* __restrict__ x, const float* __restrict__ w,
             const float* __restrict__ bias, float* __restrict__ out, int Lout)
{
    const int t  = blockIdx.x * 256 + threadIdx.x;
    const int co = blockIdx.y;
    const int b  = blockIdx.z;
    const int Lin = Lout * 2;
    const float* xb = x + (size_t)b * Lin;
    float s = bias[co];
#pragma unroll
    for (int k = 0; k < 4; ++k) {
        int ti = 2 * t - 1 + k;
        if (ti >= 0 && ti < Lin) s = fmaf(xb[ti], w[co * 4 + k], s);
    }
    out[((size_t)b * 256 + co) * Lout + t] = s;
}

// ============================================================================
// last conv transpose: 256->1 ch
// ============================================================================
__global__ __launch_bounds__(256)
void uplast_k(const float* __restrict__ in, const float* __restrict__ w,
              const float* __restrict__ bias, float* __restrict__ out, int Lin)
{
    const int m = blockIdx.x * 256 + threadIdx.x;
    const int b = blockIdx.y;
    const float bv = bias[0];
    float aE = bv, aO = bv;
    const float* inb = in + (size_t)b * 256 * Lin;
    for (int ci = 0; ci < 256; ++ci) {
        const float* row = inb + (size_t)ci * Lin;
        const float x0  = row[m];
        const float xm1 = (m > 0) ? row[m - 1] : 0.f;
        const float xp1 = (m + 1 < Lin) ? row[m + 1] : 0.f;
        const float4 wv = *(const float4*)(w + ci * 4);
        aE = fmaf(x0, wv.y, fmaf(xm1, wv.w, aE));
        aO = fmaf(xp1, wv.x, fmaf(x0, wv.z, aO));
    }
    *(float2*)(out + (size_t)b * 2 * Lin + 2 * m) = make_float2(aE, aO);
}

// ============================================================================
// transposes z[b,c,t] <-> emb[n,c]  (n = b*2048+t)
// ============================================================================
__global__ void z2emb_k(const float* __restrict__ z, float* __restrict__ emb)
{
    const int n = blockIdx.x, c = threadIdx.x;
    const int b = n >> 11, t = n & 2047;
    emb[(size_t)n * 256 + c] = z[((size_t)b * 256 + c) * 2048 + t];
}
__global__ void q2z_k(const float* __restrict__ q, float* __restrict__ z)
{
    const int n = blockIdx.x, c = threadIdx.x;
    const int b = n >> 11, t = n & 2047;
    z[((size_t)b * 256 + c) * 2048 + t] = q[(size_t)n * 256 + c];
}

// ============================================================================
// RVQ
// ============================================================================
__global__ __launch_bounds__(256)
void rvq_cb_k(const float* __restrict__ sum, const float* __restrict__ usage,
              float* __restrict__ cb, float* __restrict__ cbT,
              float* __restrict__ cbn, int iq)
{
    const int k = blockIdx.x, c = threadIdx.x;
    const float den = fmaxf(usage[iq * 1024 + k], 1e-5f);
    const float v = sum[((size_t)iq * 1024 + k) * 256 + c] / den;
    cb[(size_t)k * 256 + c] = v;
    cbT[(size_t)c * 1024 + k] = v;
    float s = v * v;
    for (int off = 32; off; off >>= 1) s += __shfl_down(s, off, 64);
    __shared__ float ls[4];
    if ((c & 63) == 0) ls[c >> 6] = s;
    __syncthreads();
    if (c == 0) cbn[k] = ls[0] + ls[1] + ls[2] + ls[3];
}

DEVFN unsigned int ordbits(float f)
{
    unsigned u = __float_as_uint(f);
    return (u & 0x80000000u) ? ~u : (u | 0x80000000u);
}
DEVFN unsigned long long shfl_xor_u64(unsigned long long v, int mask)
{
    int lo = (int)(v & 0xffffffffull), hi = (int)(v >> 32);
    lo = __shfl_xor(lo, mask, 64);
    hi = __shfl_xor(hi, mask, 64);
    return ((unsigned long long)(unsigned)hi << 32) | (unsigned)lo;
}

// block: 16 n x all 1024 k ; thread handles 4 consecutive k
__global__ __launch_bounds__(256)
void rvq_argmin_k(const float* __restrict__ emb, const float* __restrict__ q,
                  const float* __restrict__ cbT, const float* __restrict__ cbn,
                  int* __restrict__ codes, float* __restrict__ codes_out, int iq)
{
    const int n0 = blockIdx.x * 16;
    const int tid = threadIdx.x;
    __shared__ float res[16][256];
    for (int idx = tid; idx < 16 * 256; idx += 256) {
        int nl = idx >> 8, c = idx & 255;
        size_t g = (size_t)(n0 + nl) * 256 + c;
        res[nl][c] = emb[g] - q[g];
    }
    __syncthreads();
    float dot[16][4];
#pragma unroll
    for (int nl = 0; nl < 16; ++nl)
#pragma unroll
        for (int j = 0; j < 4; ++j) dot[nl][j] = 0.f;

    const float* cbtp = cbT + tid * 4;
    for (int c = 0; c < 256; ++c) {
        const float4 cbv = *(const float4*)(cbtp + (size_t)c * 1024);
#pragma unroll
        for (int nl = 0; nl < 16; ++nl) {
            const float r = res[nl][c];
            dot[nl][0] = fmaf(cbv.x, r, dot[nl][0]);
            dot[nl][1] = fmaf(cbv.y, r, dot[nl][1]);
            dot[nl][2] = fmaf(cbv.z, r, dot[nl][2]);
            dot[nl][3] = fmaf(cbv.w, r, dot[nl][3]);
        }
    }
    const float4 nrm = *(const float4*)(cbn + tid * 4);
    __shared__ unsigned long long wred[4][16];
    const int wave = tid >> 6, lane = tid & 63;
#pragma unroll
    for (int nl = 0; nl < 16; ++nl) {
        float s0 = nrm.x - 2.f * dot[nl][0];
        float s1 = nrm.y - 2.f * dot[nl][1];
        float s2 = nrm.z - 2.f * dot[nl][2];
        float s3 = nrm.w - 2.f * dot[nl][3];
        unsigned long long key =
            ((unsigned long long)ordbits(s0) << 32) | (unsigned)(tid * 4 + 0);
        unsigned long long k1 =
            ((unsigned long long)ordbits(s1) << 32) | (unsigned)(tid * 4 + 1);
        unsigned long long k2 =
            ((unsigned long long)ordbits(s2) << 32) | (unsigned)(tid * 4 + 2);
        unsigned long long k3 =
            ((unsigned long long)ordbits(s3) << 32) | (unsigned)(tid * 4 + 3);
        if (k1 < key) key = k1;
        if (k2 < key) key = k2;
        if (k3 < key) key = k3;
        for (int off = 32; off; off >>= 1) {
            unsigned long long o = shfl_xor_u64(key, off);
            if (o < key) key = o;
        }
        if (lane == 0) wred[wave][nl] = key;
    }
    __syncthreads();
    if (tid < 16) {
        unsigned long long bkey = wred[0][tid];
        if (wred[1][tid] < bkey) bkey = wred[1][tid];
        if (wred[2][tid] < bkey) bkey = wred[2][tid];
        if (wred[3][tid] < bkey) bkey = wred[3][tid];
        const int code = (int)(bkey & 0xffffffffull);
        codes[(size_t)(n0 + tid) * 8 + iq] = code;
        codes_out[(size_t)(n0 + tid) * 8 + iq] = (float)code;
    }
}

// q[n] += cb[code]; commit += sum((q_new-emb)^2)
__global__ __launch_bounds__(256)
void rvq_update_k(const float* __restrict__ emb, float* __restrict__ q,
                  const float* __restrict__ cb, const int* __restrict__ codes,
                  float* __restrict__ commit, int iq)
{
    const int n = blockIdx.x, c = threadIdx.x;
    const int code = codes[(size_t)n * 8 + iq];
    const size_t g = (size_t)n * 256 + c;
    const float qv = q[g] + cb[(size_t)code * 256 + c];
    q[g] = qv;
    const float e = qv - emb[g];
    float s = e * e;
    for (int off = 32; off; off >>= 1) s += __shfl_down(s, off, 64);
    __shared__ float ls[4];
    if ((c & 63) == 0) ls[c >> 6] = s;
    __syncthreads();
    if (c == 0) atomicAdd(commit, ls[0] + ls[1] + ls[2] + ls[3]);
}

__global__ void commit_write_k(const float* __restrict__ commit, float* __restrict__ out)
{
    out[0] = commit[0] * (1.f / (4096.f * 256.f));
}

// ============================================================================
extern "C" void kernel_launch(void* const* d_in, const int* in_sizes, int n_in,
                              void* d_out, int out_size, void* d_ws, size_t ws_size,
                              hipStream_t stream)
{
    const float* x    = (const float*)d_in[0];
    const float* ed0w = (const float*)d_in[1];
    const float* ed0b = (const float*)d_in[2];
    const float* edw  = (const float*)d_in[3];
    const float* edb  = (const float*)d_in[4];
    const float* erw  = (const float*)d_in[5];
    const float* erb  = (const float*)d_in[6];
    const float* drw  = (const float*)d_in[7];
    const float* drb  = (const float*)d_in[8];
    const float* duw  = (const float*)d_in[9];
    const float* dub  = (const float*)d_in[10];
    const float* dulw = (const float*)d_in[11];
    const float* dulb = (const float*)d_in[12];
    const float* rsum = (const float*)d_in[13];
    const float* rusg = (const float*)d_in[14];
    float* out = (float*)d_out;

    float* ws = (float*)d_ws;
    float* A      = ws;                    // 16,777,216 floats (64 MB)
    float* Bf     = A + 16777216;          // 64 MB
    float* emb    = Bf + 16777216;         // 4 MB
    float* q      = emb + 1048576;         // 4 MB
    float* commit = q + 1048576;           // 4 floats (padded)
    float* cb     = commit + 4;            // 1 MB
    float* cbT    = cb + 262144;           // 1 MB
    float* cbn    = cbT + 262144;          // 4 KB
    int*   codes  = (int*)(cbn + 1024);    // 128 KB

    static const int DIL[4] = {3, 9, 27, 81};

    // zero q + commit accumulator (ws is poisoned before every timed call)
    hipMemsetAsync(q, 0, (1048576 + 4) * sizeof(float), stream);

    // -------------------- encoder --------------------
    down0_k<<<dim3(32768 / 256, 256, 2), 256, 0, stream>>>(x, ed0w, ed0b, A, 32768);
    int L = 32768;
    for (int i = 0; i < 5; ++i) {
        if (i > 0) {
            conv4s2_k<<<dim3(L / 2 / 128, 4, 2), 256, 0, stream>>>(
                A, edw + (size_t)(i - 1) * 256 * 256 * 4, edb + (i - 1) * 256, Bf, L / 2);
            float* t = A; A = Bf; Bf = t;
            L /= 2;
        }
        for (int j = 0; j < 4; ++j) {
            const int d = DIL[j];
            const size_t u = (size_t)(i * 4 + j) * 2;
            const float* w0 = erw + (u + 0) * 256 * 256 * 3;
            const float* b0 = erb + (u + 0) * 256;
            const float* w1 = erw + (u + 1) * 256 * 256 * 3;
            const float* b1 = erb + (u + 1) * 256;
            conv3_k<<<dim3(L / 128, 4, 2), 256, 0, stream>>>(A, w0, b0, A, Bf, L, d, 0.f);
            conv3_k<<<dim3(L / 128, 4, 2), 256, 0, stream>>>(Bf, w1, b1, A, A, L, 1, 1.f);
        }
    }

    // -------------------- RVQ --------------------
    z2emb_k<<<4096, 256, 0, stream>>>(A, emb);
    for (int iq = 0; iq < 8; ++iq) {
        rvq_cb_k<<<1024, 256, 0, stream>>>(rsum, rusg, cb, cbT, cbn, iq);
        rvq_argmin_k<<<256, 256, 0, stream>>>(emb, q, cbT, cbn, codes, out + 131072, iq);
        rvq_update_k<<<4096, 256, 0, stream>>>(emb, q, cb, codes, commit, iq);
    }
    q2z_k<<<4096, 256, 0, stream>>>(q, A);

    // -------------------- decoder --------------------
    L = 2048;
    for (int i = 0; i < 5; ++i) {
        for (int j = 0; j < 4; ++j) {
            const int d = DIL[j];
            const size_t u = (size_t)(i * 4 + j) * 2;
            const float* w0 = drw + (u + 0) * 256 * 256 * 3;
            const float* b0 = drb + (u + 0) * 256;
            const float* w1 = drw + (u + 1) * 256 * 256 * 3;
            const float* b1 = drb + (u + 1) * 256;
            conv3_k<<<dim3(L / 128, 4, 2), 256, 0, stream>>>(A, w0, b0, A, Bf, L, d, 0.f);
            conv3_k<<<dim3(L / 128, 4, 2), 256, 0, stream>>>(Bf, w1, b1, A, A, L, 1, 2.f);
        }
        if (i < 4) {
            convT_k<<<dim3(L / 64, 4, 2), 256, 0, stream>>>(
                A, duw + (size_t)i * 256 * 256 * 4, dub + i * 256, Bf, L);
            float* t = A; A = Bf; Bf = t;
            L *= 2;
        } else {
            uplast_k<<<dim3(L / 256, 2), 256, 0, stream>>>(A, dulw, dulb, out, L);
        }
    }

    commit_write_k<<<1, 1, 0, stream>>>(commit, out + 163840);
}

// Round 3
// 7992.134 us; speedup vs baseline: 2.7333x; 2.7333x over previous
//
#include <hip/hip_runtime.h>
#include <cstdint>

#define DEVFN static __device__ __forceinline__
typedef unsigned short ushort_t;
typedef unsigned int uint_t;
typedef short short8 __attribute__((ext_vector_type(8)));
typedef float f32x4 __attribute__((ext_vector_type(4)));

DEVFN float bf2f(ushort_t h) { return __uint_as_float(((uint_t)h) << 16); }
DEVFN ushort_t bfhi(float f) {
    uint_t u = __float_as_uint(f);
    u += 0x7fffu + ((u >> 16) & 1u);
    return (ushort_t)(u >> 16);
}
DEVFN void fsplit(float f, ushort_t& h, ushort_t& l) {
    h = bfhi(f);
    l = bfhi(f - bf2f(h));
}
// relu on a packed pair of bf16 hi/lo dwords (2 elements each)
DEVFN void relu_pair(uint_t& h, uint_t& l) {
    float f0 = bf2f((ushort_t)(h & 0xffffu)) + bf2f((ushort_t)(l & 0xffffu));
    float f1 = bf2f((ushort_t)(h >> 16)) + bf2f((ushort_t)(l >> 16));
    if (f0 <= 0.f) { h &= 0xffff0000u; l &= 0xffff0000u; }
    if (f1 <= 0.f) { h &= 0x0000ffffu; l &= 0x0000ffffu; }
}

// ============================================================================
// weight prep: fp32 [co][ci][k] -> bf16 hi/lo [tap][co][ci]
// ============================================================================
__global__ __launch_bounds__(256)
void wprep3_k(const float* __restrict__ erw, const float* __restrict__ drw,
              ushort_t* __restrict__ wH, ushort_t* __restrict__ wL)
{
    const int gid = blockIdx.x * 256 + threadIdx.x;   // 80*65536 threads
    const int conv = gid >> 16;
    const int rem  = gid & 65535;                      // co*256+ci
    const int co = rem >> 8, ci = rem & 255;
    const float* src = (conv < 40) ? (erw + (size_t)conv * 196608)
                                   : (drw + (size_t)(conv - 40) * 196608);
    const float* p = src + ((size_t)co * 256 + ci) * 3;
    ushort_t* oh = wH + (size_t)conv * 196608 + rem;
    ushort_t* ol = wL + (size_t)conv * 196608 + rem;
#pragma unroll
    for (int k = 0; k < 3; ++k) {
        ushort_t h, l; fsplit(p[k], h, l);
        oh[k * 65536] = h; ol[k * 65536] = l;
    }
}

__global__ __launch_bounds__(256)
void wprep4_k(const float* __restrict__ edw, const float* __restrict__ duw,
              ushort_t* __restrict__ wH, ushort_t* __restrict__ wL)
{
    const int gid = blockIdx.x * 256 + threadIdx.x;   // 8*65536 threads
    const int conv = gid >> 16;
    const int rem  = gid & 65535;
    const int co = rem >> 8, ci = rem & 255;
    ushort_t* oh = wH + (size_t)conv * 262144 + rem;
    ushort_t* ol = wL + (size_t)conv * 262144 + rem;
#pragma unroll
    for (int k = 0; k < 4; ++k) {
        float f;
        // edw: [conv][out][in][k]  (co = out)
        // duw: [conv][in][out][k]  -> element (out=co, in=ci) at (ci*256+co)*4+k
        if (conv < 4)  f = edw[(size_t)conv * 262144 + ((size_t)co * 256 + ci) * 4 + k];
        else           f = duw[(size_t)(conv - 4) * 262144 + ((size_t)ci * 256 + co) * 4 + k];
        ushort_t h, l; fsplit(f, h, l);
        oh[k * 65536] = h; ol[k * 65536] = l;
    }
}

// ============================================================================
// split-precision MFMA conv: out[b,to,co] = bias + sum_{tap,ci} W x  (+alpha*src)
// act layout [b][t][256c] bf16 hi/lo. Block: 64 t x 256 co, 4 waves x 64co.
// ============================================================================
template<int TAPS, int STRIDE, bool RELU>
__global__ __launch_bounds__(256, 3)
void convs_k(const ushort_t* __restrict__ inH, const ushort_t* __restrict__ inL,
             const ushort_t* __restrict__ wH, const ushort_t* __restrict__ wL,
             const float* __restrict__ bias,
             const ushort_t* __restrict__ srcH, const ushort_t* __restrict__ srcL,
             float alpha,
             ushort_t* __restrict__ outH, ushort_t* __restrict__ outL,
             int Lin, int Lout, int dil, int pad)
{
    __shared__ __align__(16) ushort_t xsH[64][40], xsL[64][40];
    __shared__ __align__(16) ushort_t wsH[256][40], wsL[256][40];
    const int tid = threadIdx.x;
    const int b = blockIdx.z;
    const int t0 = blockIdx.x * 64;
    const int wave = tid >> 6, lane = tid & 63;
    const int quad = lane >> 4, lr = lane & 15;
    const size_t inbase = (size_t)b * Lin * 256;

    f32x4 acc[4][4];
#pragma unroll
    for (int m = 0; m < 4; ++m)
#pragma unroll
        for (int n = 0; n < 4; ++n) acc[m][n] = (f32x4)0.f;

    for (int tap = 0; tap < TAPS; ++tap) {
        const ushort_t* wHt = wH + (size_t)tap * 65536;
        const ushort_t* wLt = wL + (size_t)tap * 65536;
        for (int chunk = 0; chunk < 8; ++chunk) {
            const int ci0 = chunk * 32;
            __syncthreads();
            // ---- stage x tile: 64 rows x 32 ci ----
            {
                const int r = tid >> 2, p = tid & 3;
                const int t = STRIDE * (t0 + r) - pad + tap * dil;
                uint4 hv = make_uint4(0, 0, 0, 0), lv = hv;
                if (t >= 0 && t < Lin) {
                    const size_t g = inbase + (size_t)t * 256 + ci0 + p * 8;
                    hv = *(const uint4*)(inH + g);
                    lv = *(const uint4*)(inL + g);
                    if (RELU) {
                        relu_pair(hv.x, lv.x); relu_pair(hv.y, lv.y);
                        relu_pair(hv.z, lv.z); relu_pair(hv.w, lv.w);
                    }
                }
                *(uint4*)&xsH[r][p * 8] = hv;
                *(uint4*)&xsL[r][p * 8] = lv;
            }
            // ---- stage W tile: 256 co x 32 ci ----
#pragma unroll
            for (int it = 0; it < 4; ++it) {
                const int idx = tid + 256 * it;
                const int co = idx >> 2, p = idx & 3;
                const size_t g = (size_t)co * 256 + ci0 + p * 8;
                *(uint4*)&wsH[co][p * 8] = *(const uint4*)(wHt + g);
                *(uint4*)&wsL[co][p * 8] = *(const uint4*)(wLt + g);
            }
            __syncthreads();
            // ---- compute ----
            const int cow = wave * 64;
            short8 aH[4], aL[4];
#pragma unroll
            for (int m = 0; m < 4; ++m) {
                aH[m] = *(const short8*)&wsH[cow + m * 16 + lr][quad * 8];
                aL[m] = *(const short8*)&wsL[cow + m * 16 + lr][quad * 8];
            }
#pragma unroll
            for (int n = 0; n < 4; ++n) {
                const short8 bH = *(const short8*)&xsH[n * 16 + lr][quad * 8];
                const short8 bL = *(const short8*)&xsL[n * 16 + lr][quad * 8];
#pragma unroll
                for (int m = 0; m < 4; ++m) {
                    acc[m][n] = __builtin_amdgcn_mfma_f32_16x16x32_bf16(aH[m], bH, acc[m][n], 0, 0, 0);
                    acc[m][n] = __builtin_amdgcn_mfma_f32_16x16x32_bf16(aH[m], bL, acc[m][n], 0, 0, 0);
                    acc[m][n] = __builtin_amdgcn_mfma_f32_16x16x32_bf16(aL[m], bH, acc[m][n], 0, 0, 0);
                }
            }
        }
    }
    // ---- epilogue ----
#pragma unroll
    for (int m = 0; m < 4; ++m) {
        const int cob = wave * 64 + m * 16 + quad * 4;
        const float4 bv = *(const float4*)&bias[cob];
#pragma unroll
        for (int n = 0; n < 4; ++n) {
            const int to = t0 + n * 16 + lr;
            const size_t g = ((size_t)b * Lout + to) * 256 + cob;
            float f0 = acc[m][n][0] + bv.x;
            float f1 = acc[m][n][1] + bv.y;
            float f2 = acc[m][n][2] + bv.z;
            float f3 = acc[m][n][3] + bv.w;
            if (alpha != 0.f) {
                const ushort4 sh = *(const ushort4*)(srcH + g);
                const ushort4 sl = *(const ushort4*)(srcL + g);
                f0 += alpha * (bf2f(sh.x) + bf2f(sl.x));
                f1 += alpha * (bf2f(sh.y) + bf2f(sl.y));
                f2 += alpha * (bf2f(sh.z) + bf2f(sl.z));
                f3 += alpha * (bf2f(sh.w) + bf2f(sl.w));
            }
            ushort4 oh, ol;
            fsplit(f0, oh.x, ol.x); fsplit(f1, oh.y, ol.y);
            fsplit(f2, oh.z, ol.z); fsplit(f3, oh.w, ol.w);
            *(ushort4*)(outH + g) = oh;
            *(ushort4*)(outL + g) = ol;
        }
    }
}

// ============================================================================
// conv transpose k=4 s=2 p=1 (split MFMA). Block: 64 input m x 256 co.
// out[2m]   = x[m]w1 + x[m-1]w3 ; out[2m+1] = x[m+1]w0 + x[m]w2
// ============================================================================
__global__ __launch_bounds__(256, 2)
void convt_k(const ushort_t* __restrict__ inH, const ushort_t* __restrict__ inL,
             const ushort_t* __restrict__ wH, const ushort_t* __restrict__ wL,
             const float* __restrict__ bias,
             ushort_t* __restrict__ outH, ushort_t* __restrict__ outL, int Lin)
{
    __shared__ __align__(16) ushort_t xsH[64][40], xsL[64][40];
    __shared__ __align__(16) ushort_t wsH[256][40], wsL[256][40];
    const int tid = threadIdx.x;
    const int b = blockIdx.z;
    const int m0 = blockIdx.x * 64;
    const int Lout = Lin * 2;
    const int wave = tid >> 6, lane = tid & 63;
    const int quad = lane >> 4, lr = lane & 15;
    const size_t inbase = (size_t)b * Lin * 256;
    const int SHIFT[4] = {1, 0, 0, -1};
    const int PHASE[4] = {1, 0, 1, 0};

    f32x4 acc[4][4][2];
#pragma unroll
    for (int m = 0; m < 4; ++m)
#pragma unroll
        for (int n = 0; n < 4; ++n) { acc[m][n][0] = (f32x4)0.f; acc[m][n][1] = (f32x4)0.f; }

    for (int tap = 0; tap < 4; ++tap) {
        const ushort_t* wHt = wH + (size_t)tap * 65536;
        const ushort_t* wLt = wL + (size_t)tap * 65536;
        const int ph = PHASE[tap], sh = SHIFT[tap];
        for (int chunk = 0; chunk < 8; ++chunk) {
            const int ci0 = chunk * 32;
            __syncthreads();
            {
                const int r = tid >> 2, p = tid & 3;
                const int t = m0 + r + sh;
                uint4 hv = make_uint4(0, 0, 0, 0), lv = hv;
                if (t >= 0 && t < Lin) {
                    const size_t g = inbase + (size_t)t * 256 + ci0 + p * 8;
                    hv = *(const uint4*)(inH + g);
                    lv = *(const uint4*)(inL + g);
                }
                *(uint4*)&xsH[r][p * 8] = hv;
                *(uint4*)&xsL[r][p * 8] = lv;
            }
#pragma unroll
            for (int it = 0; it < 4; ++it) {
                const int idx = tid + 256 * it;
                const int co = idx >> 2, p = idx & 3;
                const size_t g = (size_t)co * 256 + ci0 + p * 8;
                *(uint4*)&wsH[co][p * 8] = *(const uint4*)(wHt + g);
                *(uint4*)&wsL[co][p * 8] = *(const uint4*)(wLt + g);
            }
            __syncthreads();
            const int cow = wave * 64;
            short8 aH[4], aL[4];
#pragma unroll
            for (int m = 0; m < 4; ++m) {
                aH[m] = *(const short8*)&wsH[cow + m * 16 + lr][quad * 8];
                aL[m] = *(const short8*)&wsL[cow + m * 16 + lr][quad * 8];
            }
#pragma unroll
            for (int n = 0; n < 4; ++n) {
                const short8 bH = *(const short8*)&xsH[n * 16 + lr][quad * 8];
                const short8 bL = *(const short8*)&xsL[n * 16 + lr][quad * 8];
#pragma unroll
                for (int m = 0; m < 4; ++m) {
                    acc[m][n][ph] = __builtin_amdgcn_mfma_f32_16x16x32_bf16(aH[m], bH, acc[m][n][ph], 0, 0, 0);
                    acc[m][n][ph] = __builtin_amdgcn_mfma_f32_16x16x32_bf16(aH[m], bL, acc[m][n][ph], 0, 0, 0);
                    acc[m][n][ph] = __builtin_amdgcn_mfma_f32_16x16x32_bf16(aL[m], bH, acc[m][n][ph], 0, 0, 0);
                }
            }
        }
    }
#pragma unroll
    for (int m = 0; m < 4; ++m) {
        const int cob = wave * 64 + m * 16 + quad * 4;
        const float4 bv = *(const float4*)&bias[cob];
#pragma unroll
        for (int n = 0; n < 4; ++n) {
#pragma unroll
            for (int ph = 0; ph < 2; ++ph) {
                const int to = 2 * (m0 + n * 16 + lr) + ph;
                const size_t g = ((size_t)b * Lout + to) * 256 + cob;
                ushort4 oh, ol;
                float f0 = acc[m][n][ph][0] + bv.x;
                float f1 = acc[m][n][ph][1] + bv.y;
                float f2 = acc[m][n][ph][2] + bv.z;
                float f3 = acc[m][n][ph][3] + bv.w;
                fsplit(f0, oh.x, ol.x); fsplit(f1, oh.y, ol.y);
                fsplit(f2, oh.z, ol.z); fsplit(f3, oh.w, ol.w);
                *(ushort4*)(outH + g) = oh;
                *(ushort4*)(outL + g) = ol;
            }
        }
    }
}

// ============================================================================
// first conv 1->256 k=4 s=2 p=1 ; writes [b][t][c] hi/lo
// ============================================================================
__global__ __launch_bounds__(256)
void down0_k2(const float* __restrict__ x, const float* __restrict__ w,
              const float* __restrict__ bias,
              ushort_t* __restrict__ outH, ushort_t* __restrict__ outL)
{
    const int t = blockIdx.x;               // 32768
    const int b = blockIdx.y;
    const int co = threadIdx.x;
    const float* xb = x + (size_t)b * 65536;
    const float4 wv = *(const float4*)(w + co * 4);
    float s = bias[co];
    const int ti0 = 2 * t - 1;
    if (ti0 >= 0)      s = fmaf(xb[ti0], wv.x, s);
    s = fmaf(xb[ti0 + 1], wv.y, s);
    s = fmaf(xb[ti0 + 2], wv.z, s);
    if (ti0 + 3 < 65536) s = fmaf(xb[ti0 + 3], wv.w, s);
    ushort_t h, l; fsplit(s, h, l);
    const size_t g = ((size_t)b * 32768 + t) * 256 + co;
    outH[g] = h; outL[g] = l;
}

// ============================================================================
// last conv transpose 256->1
// ============================================================================
__global__ __launch_bounds__(256)
void uplast_k2(const ushort_t* __restrict__ inH, const ushort_t* __restrict__ inL,
               const float* __restrict__ w, const float* __restrict__ bias,
               float* __restrict__ out, int Lin)
{
    const int m = blockIdx.x * 256 + threadIdx.x;
    const int b = blockIdx.y;
    const float bv = bias[0];
    float aE = bv, aO = bv;
    const size_t base = (size_t)b * Lin * 256;
    const ushort_t* r0H = inH + base + (size_t)m * 256;
    const ushort_t* r0L = inL + base + (size_t)m * 256;
    const bool hasM = (m > 0), hasP = (m + 1 < Lin);
    for (int c0 = 0; c0 < 256; c0 += 8) {
        uint4 h0 = *(const uint4*)(r0H + c0);
        uint4 l0 = *(const uint4*)(r0L + c0);
        uint4 hm = make_uint4(0,0,0,0), lm = hm, hp = hm, lp = hm;
        if (hasM) { hm = *(const uint4*)(r0H - 256 + c0); lm = *(const uint4*)(r0L - 256 + c0); }
        if (hasP) { hp = *(const uint4*)(r0H + 256 + c0); lp = *(const uint4*)(r0L + 256 + c0); }
        const uint_t* h0p = (const uint_t*)&h0; const uint_t* l0p = (const uint_t*)&l0;
        const uint_t* hmp = (const uint_t*)&hm; const uint_t* lmp = (const uint_t*)&lm;
        const uint_t* hpp = (const uint_t*)&hp; const uint_t* lpp = (const uint_t*)&lp;
#pragma unroll
        for (int e = 0; e < 4; ++e) {
#pragma unroll
            for (int half = 0; half < 2; ++half) {
                const int sh = half * 16;
                const int ci = c0 + e * 2 + half;
                const float x0  = bf2f((ushort_t)(h0p[e] >> sh)) + bf2f((ushort_t)(l0p[e] >> sh));
                const float xm1 = bf2f((ushort_t)(hmp[e] >> sh)) + bf2f((ushort_t)(lmp[e] >> sh));
                const float xp1 = bf2f((ushort_t)(hpp[e] >> sh)) + bf2f((ushort_t)(lpp[e] >> sh));
                const float4 wv = *(const float4*)(w + ci * 4);
                aE = fmaf(x0, wv.y, fmaf(xm1, wv.w, aE));
                aO = fmaf(xp1, wv.x, fmaf(x0, wv.z, aO));
            }
        }
    }
    *(float2*)(out + (size_t)b * 2 * Lin + 2 * m) = make_float2(aE, aO);
}

// ============================================================================
// act <-> fp32 emb/q
// ============================================================================
__global__ void emb_k(const ushort_t* __restrict__ H, const ushort_t* __restrict__ L,
                      float* __restrict__ emb)
{
    const size_t g = (size_t)blockIdx.x * 256 + threadIdx.x;
    emb[g] = bf2f(H[g]) + bf2f(L[g]);
}
__global__ void qsplit_k(const float* __restrict__ q,
                         ushort_t* __restrict__ H, ushort_t* __restrict__ L)
{
    const size_t g = (size_t)blockIdx.x * 256 + threadIdx.x;
    ushort_t h, l; fsplit(q[g], h, l);
    H[g] = h; L[g] = l;
}

// ============================================================================
// RVQ (fp32)
// ============================================================================
__global__ __launch_bounds__(256)
void rvq_cb_k(const float* __restrict__ sum, const float* __restrict__ usage,
              float* __restrict__ cb, float* __restrict__ cbT,
              float* __restrict__ cbn, int iq)
{
    const int k = blockIdx.x, c = threadIdx.x;
    const float den = fmaxf(usage[iq * 1024 + k], 1e-5f);
    const float v = sum[((size_t)iq * 1024 + k) * 256 + c] / den;
    cb[(size_t)k * 256 + c] = v;
    cbT[(size_t)c * 1024 + k] = v;
    float s = v * v;
    for (int off = 32; off; off >>= 1) s += __shfl_down(s, off, 64);
    __shared__ float ls[4];
    if ((c & 63) == 0) ls[c >> 6] = s;
    __syncthreads();
    if (c == 0) cbn[k] = ls[0] + ls[1] + ls[2] + ls[3];
}

DEVFN unsigned int ordbits(float f)
{
    unsigned u = __float_as_uint(f);
    return (u & 0x80000000u) ? ~u : (u | 0x80000000u);
}
DEVFN unsigned long long shfl_xor_u64(unsigned long long v, int mask)
{
    int lo = (int)(v & 0xffffffffull), hi = (int)(v >> 32);
    lo = __shfl_xor(lo, mask, 64);
    hi = __shfl_xor(hi, mask, 64);
    return ((unsigned long long)(unsigned)hi << 32) | (unsigned)lo;
}

__global__ __launch_bounds__(256)
void rvq_argmin_k(const float* __restrict__ emb, const float* __restrict__ q,
                  const float* __restrict__ cbT, const float* __restrict__ cbn,
                  int* __restrict__ codes, float* __restrict__ codes_out, int iq)
{
    const int n0 = blockIdx.x * 16;
    const int tid = threadIdx.x;
    __shared__ float res[16][256];
    for (int idx = tid; idx < 16 * 256; idx += 256) {
        int nl = idx >> 8, c = idx & 255;
        size_t g = (size_t)(n0 + nl) * 256 + c;
        res[nl][c] = emb[g] - q[g];
    }
    __syncthreads();
    float dot[16][4];
#pragma unroll
    for (int nl = 0; nl < 16; ++nl)
#pragma unroll
        for (int j = 0; j < 4; ++j) dot[nl][j] = 0.f;

    const float* cbtp = cbT + tid * 4;
    for (int c = 0; c < 256; ++c) {
        const float4 cbv = *(const float4*)(cbtp + (size_t)c * 1024);
#pragma unroll
        for (int nl = 0; nl < 16; ++nl) {
            const float r = res[nl][c];
            dot[nl][0] = fmaf(cbv.x, r, dot[nl][0]);
            dot[nl][1] = fmaf(cbv.y, r, dot[nl][1]);
            dot[nl][2] = fmaf(cbv.z, r, dot[nl][2]);
            dot[nl][3] = fmaf(cbv.w, r, dot[nl][3]);
        }
    }
    const float4 nrm = *(const float4*)(cbn + tid * 4);
    __shared__ unsigned long long wred[4][16];
    const int wave = tid >> 6, lane = tid & 63;
#pragma unroll
    for (int nl = 0; nl < 16; ++nl) {
        float s0 = nrm.x - 2.f * dot[nl][0];
        float s1 = nrm.y - 2.f * dot[nl][1];
        float s2 = nrm.z - 2.f * dot[nl][2];
        float s3 = nrm.w - 2.f * dot[nl][3];
        unsigned long long key =
            ((unsigned long long)ordbits(s0) << 32) | (unsigned)(tid * 4 + 0);
        unsigned long long k1 =
            ((unsigned long long)ordbits(s1) << 32) | (unsigned)(tid * 4 + 1);
        unsigned long long k2 =
            ((unsigned long long)ordbits(s2) << 32) | (unsigned)(tid * 4 + 2);
        unsigned long long k3 =
            ((unsigned long long)ordbits(s3) << 32) | (unsigned)(tid * 4 + 3);
        if (k1 < key) key = k1;
        if (k2 < key) key = k2;
        if (k3 < key) key = k3;
        for (int off = 32; off; off >>= 1) {
            unsigned long long o = shfl_xor_u64(key, off);
            if (o < key) key = o;
        }
        if (lane == 0) wred[wave][nl] = key;
    }
    __syncthreads();
    if (tid < 16) {
        unsigned long long bkey = wred[0][tid];
        if (wred[1][tid] < bkey) bkey = wred[1][tid];
        if (wred[2][tid] < bkey) bkey = wred[2][tid];
        if (wred[3][tid] < bkey) bkey = wred[3][tid];
        const int code = (int)(bkey & 0xffffffffull);
        codes[(size_t)(n0 + tid) * 8 + iq] = code;
        codes_out[(size_t)(n0 + tid) * 8 + iq] = (float)code;
    }
}

__global__ __launch_bounds__(256)
void rvq_update_k(const float* __restrict__ emb, float* __restrict__ q,
                  const float* __restrict__ cb, const int* __restrict__ codes,
                  float* __restrict__ commit, int iq)
{
    const int n = blockIdx.x, c = threadIdx.x;
    const int code = codes[(size_t)n * 8 + iq];
    const size_t g = (size_t)n * 256 + c;
    const float qv = q[g] + cb[(size_t)code * 256 + c];
    q[g] = qv;
    const float e = qv - emb[g];
    float s = e * e;
    for (int off = 32; off; off >>= 1) s += __shfl_down(s, off, 64);
    __shared__ float ls[4];
    if ((c & 63) == 0) ls[c >> 6] = s;
    __syncthreads();
    if (c == 0) atomicAdd(commit, ls[0] + ls[1] + ls[2] + ls[3]);
}

__global__ void commit_write_k(const float* __restrict__ commit, float* __restrict__ out)
{
    out[0] = commit[0] * (1.f / (4096.f * 256.f));
}

// ============================================================================
extern "C" void kernel_launch(void* const* d_in, const int* in_sizes, int n_in,
                              void* d_out, int out_size, void* d_ws, size_t ws_size,
                              hipStream_t stream)
{
    const float* x    = (const float*)d_in[0];
    const float* ed0w = (const float*)d_in[1];
    const float* ed0b = (const float*)d_in[2];
    const float* edw  = (const float*)d_in[3];
    const float* edb  = (const float*)d_in[4];
    const float* erw  = (const float*)d_in[5];
    const float* erb  = (const float*)d_in[6];
    const float* drw  = (const float*)d_in[7];
    const float* drb  = (const float*)d_in[8];
    const float* duw  = (const float*)d_in[9];
    const float* dub  = (const float*)d_in[10];
    const float* dulw = (const float*)d_in[11];
    const float* dulb = (const float*)d_in[12];
    const float* rsum = (const float*)d_in[13];
    const float* rusg = (const float*)d_in[14];
    float* out = (float*)d_out;

    char* base = (char*)d_ws;
    size_t o = 0;
    ushort_t* wH3 = (ushort_t*)(base + o); o += 31457280;   // 80*3*65536 bf16
    ushort_t* wL3 = (ushort_t*)(base + o); o += 31457280;
    ushort_t* w4H = (ushort_t*)(base + o); o += 4194304;    // 8*4*65536 bf16
    ushort_t* w4L = (ushort_t*)(base + o); o += 4194304;
    ushort_t* AH  = (ushort_t*)(base + o); o += 33554432;   // act [2][32768][256]
    ushort_t* AL  = (ushort_t*)(base + o); o += 33554432;
    ushort_t* BH  = (ushort_t*)(base + o); o += 33554432;
    ushort_t* BL  = (ushort_t*)(base + o); o += 33554432;
    float* emb    = (float*)(base + o);    o += 4194304;
    float* q      = (float*)(base + o);    o += 4194304;
    float* commit = (float*)(base + o);    o += 64;
    float* cb     = (float*)(base + o);    o += 1048576;
    float* cbT    = (float*)(base + o);    o += 1048576;
    float* cbn    = (float*)(base + o);    o += 4096;
    int*   codes  = (int*)(base + o);      o += 131072;

    static const int DIL[4] = {3, 9, 27, 81};

    hipMemsetAsync(q, 0, 4194304 + 64, stream);   // q + commit

    // weight prep
    wprep3_k<<<20480, 256, 0, stream>>>(erw, drw, wH3, wL3);
    wprep4_k<<<2048, 256, 0, stream>>>(edw, duw, w4H, w4L);

    // -------------------- encoder --------------------
    down0_k2<<<dim3(32768, 2), 256, 0, stream>>>(x, ed0w, ed0b, AH, AL);
    int L = 32768;
    for (int i = 0; i < 5; ++i) {
        if (i > 0) {
            const ushort_t* wh = w4H + (size_t)(i - 1) * 262144;
            const ushort_t* wl = w4L + (size_t)(i - 1) * 262144;
            convs_k<4, 2, false><<<dim3(L / 2 / 64, 1, 2), 256, 0, stream>>>(
                AH, AL, wh, wl, edb + (i - 1) * 256, AH, AL, 0.f, BH, BL, L, L / 2, 1, 1);
            ushort_t* t;
            t = AH; AH = BH; BH = t;
            t = AL; AL = BL; BL = t;
            L /= 2;
        }
        for (int j = 0; j < 4; ++j) {
            const int d = DIL[j];
            const size_t u = (size_t)(i * 4 + j) * 2;
            convs_k<3, 1, true><<<dim3(L / 64, 1, 2), 256, 0, stream>>>(
                AH, AL, wH3 + (u + 0) * 196608, wL3 + (u + 0) * 196608, erb + (u + 0) * 256,
                AH, AL, 0.f, BH, BL, L, L, d, d);
            convs_k<3, 1, true><<<dim3(L / 64, 1, 2), 256, 0, stream>>>(
                BH, BL, wH3 + (u + 1) * 196608, wL3 + (u + 1) * 196608, erb + (u + 1) * 256,
                AH, AL, 1.f, AH, AL, L, L, 1, 1);
        }
    }

    // -------------------- RVQ --------------------
    emb_k<<<4096, 256, 0, stream>>>(AH, AL, emb);
    for (int iq = 0; iq < 8; ++iq) {
        rvq_cb_k<<<1024, 256, 0, stream>>>(rsum, rusg, cb, cbT, cbn, iq);
        rvq_argmin_k<<<256, 256, 0, stream>>>(emb, q, cbT, cbn, codes, out + 131072, iq);
        rvq_update_k<<<4096, 256, 0, stream>>>(emb, q, cb, codes, commit, iq);
    }
    qsplit_k<<<4096, 256, 0, stream>>>(q, AH, AL);

    // -------------------- decoder --------------------
    L = 2048;
    for (int i = 0; i < 5; ++i) {
        for (int j = 0; j < 4; ++j) {
            const int d = DIL[j];
            // decoder conv slab indices are 40..79: conv = 40 + (i*4+j)*2 + {0,1}
            const size_t u = 40 + (size_t)(i * 4 + j) * 2;
            convs_k<3, 1, true><<<dim3(L / 64, 1, 2), 256, 0, stream>>>(
                AH, AL, wH3 + (u + 0) * 196608, wL3 + (u + 0) * 196608,
                drb + ((size_t)(i * 4 + j) * 2 + 0) * 256,
                AH, AL, 0.f, BH, BL, L, L, d, d);
            convs_k<3, 1, true><<<dim3(L / 64, 1, 2), 256, 0, stream>>>(
                BH, BL, wH3 + (u + 1) * 196608, wL3 + (u + 1) * 196608,
                drb + ((size_t)(i * 4 + j) * 2 + 1) * 256,
                AH, AL, 2.f, AH, AL, L, L, 1, 1);
        }
        if (i < 4) {
            const ushort_t* wh = w4H + (size_t)(4 + i) * 262144;
            const ushort_t* wl = w4L + (size_t)(4 + i) * 262144;
            convt_k<<<dim3(L / 64, 1, 2), 256, 0, stream>>>(
                AH, AL, wh, wl, dub + i * 256, BH, BL, L);
            ushort_t* t;
            t = AH; AH = BH; BH = t;
            t = AL; AL = BL; BL = t;
            L *= 2;
        } else {
            uplast_k2<<<dim3(L / 256, 2), 256, 0, stream>>>(AH, AL, dulw, dulb, out, L);
        }
    }

    commit_write_k<<<1, 1, 0, stream>>>(commit, out + 163840);
}

// Round 4
// 7614.284 us; speedup vs baseline: 2.8689x; 1.0496x over previous
//
#include <hip/hip_runtime.h>
#include <cstdint>

#define DEVFN static __device__ __forceinline__
typedef unsigned short ushort_t;
typedef unsigned int uint_t;
typedef short short8 __attribute__((ext_vector_type(8)));
typedef float f32x4 __attribute__((ext_vector_type(4)));

DEVFN float bf2f(ushort_t h) { return __uint_as_float(((uint_t)h) << 16); }
DEVFN ushort_t bfhi(float f) {
    uint_t u = __float_as_uint(f);
    u += 0x7fffu + ((u >> 16) & 1u);
    return (ushort_t)(u >> 16);
}
DEVFN void fsplit(float f, ushort_t& h, ushort_t& l) {
    h = bfhi(f);
    l = bfhi(f - bf2f(h));
}
// relu on a packed pair of bf16 hi/lo dwords (2 elements each)
DEVFN void relu_pair(uint_t& h, uint_t& l) {
    float f0 = bf2f((ushort_t)(h & 0xffffu)) + bf2f((ushort_t)(l & 0xffffu));
    float f1 = bf2f((ushort_t)(h >> 16)) + bf2f((ushort_t)(l >> 16));
    if (f0 <= 0.f) { h &= 0xffff0000u; l &= 0xffff0000u; }
    if (f1 <= 0.f) { h &= 0x0000ffffu; l &= 0x0000ffffu; }
}

// ============================================================================
// weight prep: fp32 [co][ci][k] -> bf16 hi/lo [tap][co][ci]
// ============================================================================
__global__ __launch_bounds__(256)
void wprep3_k(const float* __restrict__ erw, const float* __restrict__ drw,
              ushort_t* __restrict__ wH, ushort_t* __restrict__ wL)
{
    const int gid = blockIdx.x * 256 + threadIdx.x;   // 80*65536 threads
    const int conv = gid >> 16;
    const int rem  = gid & 65535;                      // co*256+ci
    const int co = rem >> 8, ci = rem & 255;
    const float* src = (conv < 40) ? (erw + (size_t)conv * 196608)
                                   : (drw + (size_t)(conv - 40) * 196608);
    const float* p = src + ((size_t)co * 256 + ci) * 3;
    ushort_t* oh = wH + (size_t)conv * 196608 + rem;
    ushort_t* ol = wL + (size_t)conv * 196608 + rem;
#pragma unroll
    for (int k = 0; k < 3; ++k) {
        ushort_t h, l; fsplit(p[k], h, l);
        oh[k * 65536] = h; ol[k * 65536] = l;
    }
}

__global__ __launch_bounds__(256)
void wprep4_k(const float* __restrict__ edw, const float* __restrict__ duw,
              ushort_t* __restrict__ wH, ushort_t* __restrict__ wL)
{
    const int gid = blockIdx.x * 256 + threadIdx.x;   // 8*65536 threads
    const int conv = gid >> 16;
    const int rem  = gid & 65535;
    const int co = rem >> 8, ci = rem & 255;
    ushort_t* oh = wH + (size_t)conv * 262144 + rem;
    ushort_t* ol = wL + (size_t)conv * 262144 + rem;
#pragma unroll
    for (int k = 0; k < 4; ++k) {
        float f;
        // edw: [conv][out][in][k]  (co = out)
        // duw: [conv][in][out][k]  -> element (out=co, in=ci) at (ci*256+co)*4+k
        if (conv < 4)  f = edw[(size_t)conv * 262144 + ((size_t)co * 256 + ci) * 4 + k];
        else           f = duw[(size_t)(conv - 4) * 262144 + ((size_t)ci * 256 + co) * 4 + k];
        ushort_t h, l; fsplit(f, h, l);
        oh[k * 65536] = h; ol[k * 65536] = l;
    }
}

// ============================================================================
// split-precision MFMA conv: out[b,to,co] = bias + sum_{tap,ci} W x  (+alpha*src)
// act layout [b][t][256c] bf16 hi/lo. Block: 64 t x 256 co, 4 waves x 64co.
// Epilogue: fp32 acc -> LDS tile -> coalesced contiguous-row stores.
// ============================================================================
template<int TAPS, int STRIDE, bool RELU>
__global__ __launch_bounds__(256, 3)
void convs_k(const ushort_t* __restrict__ inH, const ushort_t* __restrict__ inL,
             const ushort_t* __restrict__ wH, const ushort_t* __restrict__ wL,
             const float* __restrict__ bias,
             const ushort_t* __restrict__ srcH, const ushort_t* __restrict__ srcL,
             float alpha,
             ushort_t* __restrict__ outH, ushort_t* __restrict__ outL,
             int Lin, int Lout, int dil, int pad)
{
    __shared__ __align__(16) char sarena[51200];
    ushort_t (*xsH)[40] = (ushort_t(*)[40])(sarena);            // 64 x 40
    ushort_t (*xsL)[40] = (ushort_t(*)[40])(sarena + 5120);
    ushort_t (*wsH)[40] = (ushort_t(*)[40])(sarena + 10240);    // 256 x 40
    ushort_t (*wsL)[40] = (ushort_t(*)[40])(sarena + 30720);

    const int tid = threadIdx.x;
    const int b = blockIdx.z;
    const int t0 = blockIdx.x * 64;
    const int wave = tid >> 6, lane = tid & 63;
    const int quad = lane >> 4, lr = lane & 15;
    const size_t inbase = (size_t)b * Lin * 256;

    f32x4 acc[4][4];
#pragma unroll
    for (int m = 0; m < 4; ++m)
#pragma unroll
        for (int n = 0; n < 4; ++n) acc[m][n] = (f32x4)0.f;

    for (int tap = 0; tap < TAPS; ++tap) {
        const ushort_t* wHt = wH + (size_t)tap * 65536;
        const ushort_t* wLt = wL + (size_t)tap * 65536;
        for (int chunk = 0; chunk < 8; ++chunk) {
            const int ci0 = chunk * 32;
            __syncthreads();
            // ---- stage x tile: 64 rows x 32 ci ----
            {
                const int r = tid >> 2, p = tid & 3;
                const int t = STRIDE * (t0 + r) - pad + tap * dil;
                uint4 hv = make_uint4(0, 0, 0, 0), lv = hv;
                if (t >= 0 && t < Lin) {
                    const size_t g = inbase + (size_t)t * 256 + ci0 + p * 8;
                    hv = *(const uint4*)(inH + g);
                    lv = *(const uint4*)(inL + g);
                    if (RELU) {
                        relu_pair(hv.x, lv.x); relu_pair(hv.y, lv.y);
                        relu_pair(hv.z, lv.z); relu_pair(hv.w, lv.w);
                    }
                }
                *(uint4*)&xsH[r][p * 8] = hv;
                *(uint4*)&xsL[r][p * 8] = lv;
            }
            // ---- stage W tile: 256 co x 32 ci ----
#pragma unroll
            for (int it = 0; it < 4; ++it) {
                const int idx = tid + 256 * it;
                const int co = idx >> 2, p = idx & 3;
                const size_t g = (size_t)co * 256 + ci0 + p * 8;
                *(uint4*)&wsH[co][p * 8] = *(const uint4*)(wHt + g);
                *(uint4*)&wsL[co][p * 8] = *(const uint4*)(wLt + g);
            }
            __syncthreads();
            // ---- compute ----
            const int cow = wave * 64;
            short8 aH[4], aL[4];
#pragma unroll
            for (int m = 0; m < 4; ++m) {
                aH[m] = *(const short8*)&wsH[cow + m * 16 + lr][quad * 8];
                aL[m] = *(const short8*)&wsL[cow + m * 16 + lr][quad * 8];
            }
#pragma unroll
            for (int n = 0; n < 4; ++n) {
                const short8 bH = *(const short8*)&xsH[n * 16 + lr][quad * 8];
                const short8 bL = *(const short8*)&xsL[n * 16 + lr][quad * 8];
#pragma unroll
                for (int m = 0; m < 4; ++m) {
                    acc[m][n] = __builtin_amdgcn_mfma_f32_16x16x32_bf16(aH[m], bH, acc[m][n], 0, 0, 0);
                    acc[m][n] = __builtin_amdgcn_mfma_f32_16x16x32_bf16(aH[m], bL, acc[m][n], 0, 0, 0);
                    acc[m][n] = __builtin_amdgcn_mfma_f32_16x16x32_bf16(aL[m], bH, acc[m][n], 0, 0, 0);
                }
            }
        }
    }
    // ---- coalesced epilogue ----
    float4 bvv[4];
    {
        const int cow = wave * 64;
#pragma unroll
        for (int m = 0; m < 4; ++m)
            bvv[m] = *(const float4*)&bias[cow + m * 16 + quad * 4];
    }
    __syncthreads();
    float (*ebuf)[260] = (float(*)[260])sarena;   // 16 rows x 260 cols
    const int cow = wave * 64;
#pragma unroll
    for (int n = 0; n < 4; ++n) {
#pragma unroll
        for (int m = 0; m < 4; ++m) {
            float4 v;
            v.x = acc[m][n][0] + bvv[m].x;
            v.y = acc[m][n][1] + bvv[m].y;
            v.z = acc[m][n][2] + bvv[m].z;
            v.w = acc[m][n][3] + bvv[m].w;
            *(float4*)&ebuf[lr][cow + m * 16 + quad * 4] = v;
        }
        __syncthreads();
        {
            const int row = tid >> 4;
            const int c00 = (tid & 15) * 4;
            const int t = t0 + n * 16 + row;
            const size_t gr = ((size_t)b * Lout + t) * 256;
#pragma unroll
            for (int rep = 0; rep < 4; ++rep) {
                const int col = c00 + rep * 64;
                float4 v = *(const float4*)&ebuf[row][col];
                if (alpha != 0.f) {
                    const ushort4 sh = *(const ushort4*)(srcH + gr + col);
                    const ushort4 sl = *(const ushort4*)(srcL + gr + col);
                    v.x += alpha * (bf2f(sh.x) + bf2f(sl.x));
                    v.y += alpha * (bf2f(sh.y) + bf2f(sl.y));
                    v.z += alpha * (bf2f(sh.z) + bf2f(sl.z));
                    v.w += alpha * (bf2f(sh.w) + bf2f(sl.w));
                }
                ushort4 oh, ol;
                fsplit(v.x, oh.x, ol.x); fsplit(v.y, oh.y, ol.y);
                fsplit(v.z, oh.z, ol.z); fsplit(v.w, oh.w, ol.w);
                *(ushort4*)(outH + gr + col) = oh;
                *(ushort4*)(outL + gr + col) = ol;
            }
        }
        __syncthreads();
    }
}

// ============================================================================
// conv transpose k=4 s=2 p=1 (split MFMA). Block: 64 input m x 256 co.
// out[2m]   = x[m]w1 + x[m-1]w3 ; out[2m+1] = x[m+1]w0 + x[m]w2
// ============================================================================
__global__ __launch_bounds__(256, 2)
void convt_k(const ushort_t* __restrict__ inH, const ushort_t* __restrict__ inL,
             const ushort_t* __restrict__ wH, const ushort_t* __restrict__ wL,
             const float* __restrict__ bias,
             ushort_t* __restrict__ outH, ushort_t* __restrict__ outL, int Lin)
{
    __shared__ __align__(16) char sarena[51200];
    ushort_t (*xsH)[40] = (ushort_t(*)[40])(sarena);
    ushort_t (*xsL)[40] = (ushort_t(*)[40])(sarena + 5120);
    ushort_t (*wsH)[40] = (ushort_t(*)[40])(sarena + 10240);
    ushort_t (*wsL)[40] = (ushort_t(*)[40])(sarena + 30720);

    const int tid = threadIdx.x;
    const int b = blockIdx.z;
    const int m0 = blockIdx.x * 64;
    const int Lout = Lin * 2;
    const int wave = tid >> 6, lane = tid & 63;
    const int quad = lane >> 4, lr = lane & 15;
    const size_t inbase = (size_t)b * Lin * 256;
    const int SHIFT[4] = {1, 0, 0, -1};
    const int PHASE[4] = {1, 0, 1, 0};

    f32x4 acc[4][4][2];
#pragma unroll
    for (int m = 0; m < 4; ++m)
#pragma unroll
        for (int n = 0; n < 4; ++n) { acc[m][n][0] = (f32x4)0.f; acc[m][n][1] = (f32x4)0.f; }

    for (int tap = 0; tap < 4; ++tap) {
        const ushort_t* wHt = wH + (size_t)tap * 65536;
        const ushort_t* wLt = wL + (size_t)tap * 65536;
        const int ph = PHASE[tap], sh = SHIFT[tap];
        for (int chunk = 0; chunk < 8; ++chunk) {
            const int ci0 = chunk * 32;
            __syncthreads();
            {
                const int r = tid >> 2, p = tid & 3;
                const int t = m0 + r + sh;
                uint4 hv = make_uint4(0, 0, 0, 0), lv = hv;
                if (t >= 0 && t < Lin) {
                    const size_t g = inbase + (size_t)t * 256 + ci0 + p * 8;
                    hv = *(const uint4*)(inH + g);
                    lv = *(const uint4*)(inL + g);
                }
                *(uint4*)&xsH[r][p * 8] = hv;
                *(uint4*)&xsL[r][p * 8] = lv;
            }
#pragma unroll
            for (int it = 0; it < 4; ++it) {
                const int idx = tid + 256 * it;
                const int co = idx >> 2, p = idx & 3;
                const size_t g = (size_t)co * 256 + ci0 + p * 8;
                *(uint4*)&wsH[co][p * 8] = *(const uint4*)(wHt + g);
                *(uint4*)&wsL[co][p * 8] = *(const uint4*)(wLt + g);
            }
            __syncthreads();
            const int cow = wave * 64;
            short8 aH[4], aL[4];
#pragma unroll
            for (int m = 0; m < 4; ++m) {
                aH[m] = *(const short8*)&wsH[cow + m * 16 + lr][quad * 8];
                aL[m] = *(const short8*)&wsL[cow + m * 16 + lr][quad * 8];
            }
#pragma unroll
            for (int n = 0; n < 4; ++n) {
                const short8 bH = *(const short8*)&xsH[n * 16 + lr][quad * 8];
                const short8 bL = *(const short8*)&xsL[n * 16 + lr][quad * 8];
#pragma unroll
                for (int m = 0; m < 4; ++m) {
                    acc[m][n][ph] = __builtin_amdgcn_mfma_f32_16x16x32_bf16(aH[m], bH, acc[m][n][ph], 0, 0, 0);
                    acc[m][n][ph] = __builtin_amdgcn_mfma_f32_16x16x32_bf16(aH[m], bL, acc[m][n][ph], 0, 0, 0);
                    acc[m][n][ph] = __builtin_amdgcn_mfma_f32_16x16x32_bf16(aL[m], bH, acc[m][n][ph], 0, 0, 0);
                }
            }
        }
    }
    // ---- coalesced epilogue: 32 output rows per n-group ----
    float4 bvv[4];
    {
        const int cow = wave * 64;
#pragma unroll
        for (int m = 0; m < 4; ++m)
            bvv[m] = *(const float4*)&bias[cow + m * 16 + quad * 4];
    }
    __syncthreads();
    float (*ebuf)[260] = (float(*)[260])sarena;   // 32 rows x 260 cols
    const int cow = wave * 64;
#pragma unroll
    for (int n = 0; n < 4; ++n) {
#pragma unroll
        for (int m = 0; m < 4; ++m) {
#pragma unroll
            for (int ph = 0; ph < 2; ++ph) {
                float4 v;
                v.x = acc[m][n][ph][0] + bvv[m].x;
                v.y = acc[m][n][ph][1] + bvv[m].y;
                v.z = acc[m][n][ph][2] + bvv[m].z;
                v.w = acc[m][n][ph][3] + bvv[m].w;
                *(float4*)&ebuf[2 * lr + ph][cow + m * 16 + quad * 4] = v;
            }
        }
        __syncthreads();
        {
            const int baset = 2 * (m0 + n * 16);
#pragma unroll
            for (int h = 0; h < 8; ++h) {
                const int row = (tid >> 4) + 16 * (h >> 2);
                const int col = (tid & 15) * 4 + (h & 3) * 64;
                const int t = baset + row;
                const size_t gr = ((size_t)b * Lout + t) * 256 + col;
                float4 v = *(const float4*)&ebuf[row][col];
                ushort4 oh, ol;
                fsplit(v.x, oh.x, ol.x); fsplit(v.y, oh.y, ol.y);
                fsplit(v.z, oh.z, ol.z); fsplit(v.w, oh.w, ol.w);
                *(ushort4*)(outH + gr) = oh;
                *(ushort4*)(outL + gr) = ol;
            }
        }
        __syncthreads();
    }
}

// ============================================================================
// first conv 1->256 k=4 s=2 p=1 ; writes [b][t][c] hi/lo
// ============================================================================
__global__ __launch_bounds__(256)
void down0_k2(const float* __restrict__ x, const float* __restrict__ w,
              const float* __restrict__ bias,
              ushort_t* __restrict__ outH, ushort_t* __restrict__ outL)
{
    const int t = blockIdx.x;               // 32768
    const int b = blockIdx.y;
    const int co = threadIdx.x;
    const float* xb = x + (size_t)b * 65536;
    const float4 wv = *(const float4*)(w + co * 4);
    float s = bias[co];
    const int ti0 = 2 * t - 1;
    if (ti0 >= 0)      s = fmaf(xb[ti0], wv.x, s);
    s = fmaf(xb[ti0 + 1], wv.y, s);
    s = fmaf(xb[ti0 + 2], wv.z, s);
    if (ti0 + 3 < 65536) s = fmaf(xb[ti0 + 3], wv.w, s);
    ushort_t h, l; fsplit(s, h, l);
    const size_t g = ((size_t)b * 32768 + t) * 256 + co;
    outH[g] = h; outL[g] = l;
}

// ============================================================================
// last conv transpose 256->1
// ============================================================================
__global__ __launch_bounds__(256)
void uplast_k2(const ushort_t* __restrict__ inH, const ushort_t* __restrict__ inL,
               const float* __restrict__ w, const float* __restrict__ bias,
               float* __restrict__ out, int Lin)
{
    const int m = blockIdx.x * 256 + threadIdx.x;
    const int b = blockIdx.y;
    const float bv = bias[0];
    float aE = bv, aO = bv;
    const size_t base = (size_t)b * Lin * 256;
    const ushort_t* r0H = inH + base + (size_t)m * 256;
    const ushort_t* r0L = inL + base + (size_t)m * 256;
    const bool hasM = (m > 0), hasP = (m + 1 < Lin);
    for (int c0 = 0; c0 < 256; c0 += 8) {
        uint4 h0 = *(const uint4*)(r0H + c0);
        uint4 l0 = *(const uint4*)(r0L + c0);
        uint4 hm = make_uint4(0,0,0,0), lm = hm, hp = hm, lp = hm;
        if (hasM) { hm = *(const uint4*)(r0H - 256 + c0); lm = *(const uint4*)(r0L - 256 + c0); }
        if (hasP) { hp = *(const uint4*)(r0H + 256 + c0); lp = *(const uint4*)(r0L + 256 + c0); }
        const uint_t* h0p = (const uint_t*)&h0; const uint_t* l0p = (const uint_t*)&l0;
        const uint_t* hmp = (const uint_t*)&hm; const uint_t* lmp = (const uint_t*)&lm;
        const uint_t* hpp = (const uint_t*)&hp; const uint_t* lpp = (const uint_t*)&lp;
#pragma unroll
        for (int e = 0; e < 4; ++e) {
#pragma unroll
            for (int half = 0; half < 2; ++half) {
                const int sh = half * 16;
                const int ci = c0 + e * 2 + half;
                const float x0  = bf2f((ushort_t)(h0p[e] >> sh)) + bf2f((ushort_t)(l0p[e] >> sh));
                const float xm1 = bf2f((ushort_t)(hmp[e] >> sh)) + bf2f((ushort_t)(lmp[e] >> sh));
                const float xp1 = bf2f((ushort_t)(hpp[e] >> sh)) + bf2f((ushort_t)(lpp[e] >> sh));
                const float4 wv = *(const float4*)(w + ci * 4);
                aE = fmaf(x0, wv.y, fmaf(xm1, wv.w, aE));
                aO = fmaf(xp1, wv.x, fmaf(x0, wv.z, aO));
            }
        }
    }
    *(float2*)(out + (size_t)b * 2 * Lin + 2 * m) = make_float2(aE, aO);
}

// ============================================================================
// act <-> fp32 emb/q
// ============================================================================
__global__ void emb_k(const ushort_t* __restrict__ H, const ushort_t* __restrict__ L,
                      float* __restrict__ emb)
{
    const size_t g = (size_t)blockIdx.x * 256 + threadIdx.x;
    emb[g] = bf2f(H[g]) + bf2f(L[g]);
}
__global__ void qsplit_k(const float* __restrict__ q,
                         ushort_t* __restrict__ H, ushort_t* __restrict__ L)
{
    const size_t g = (size_t)blockIdx.x * 256 + threadIdx.x;
    ushort_t h, l; fsplit(q[g], h, l);
    H[g] = h; L[g] = l;
}

// ============================================================================
// RVQ (fp32)
// ============================================================================
__global__ __launch_bounds__(256)
void rvq_cb_k(const float* __restrict__ sum, const float* __restrict__ usage,
              float* __restrict__ cb, float* __restrict__ cbT,
              float* __restrict__ cbn, int iq)
{
    const int k = blockIdx.x, c = threadIdx.x;
    const float den = fmaxf(usage[iq * 1024 + k], 1e-5f);
    const float v = sum[((size_t)iq * 1024 + k) * 256 + c] / den;
    cb[(size_t)k * 256 + c] = v;
    cbT[(size_t)c * 1024 + k] = v;
    float s = v * v;
    for (int off = 32; off; off >>= 1) s += __shfl_down(s, off, 64);
    __shared__ float ls[4];
    if ((c & 63) == 0) ls[c >> 6] = s;
    __syncthreads();
    if (c == 0) cbn[k] = ls[0] + ls[1] + ls[2] + ls[3];
}

DEVFN unsigned int ordbits(float f)
{
    unsigned u = __float_as_uint(f);
    return (u & 0x80000000u) ? ~u : (u | 0x80000000u);
}
DEVFN unsigned long long shfl_xor_u64(unsigned long long v, int mask)
{
    int lo = (int)(v & 0xffffffffull), hi = (int)(v >> 32);
    lo = __shfl_xor(lo, mask, 64);
    hi = __shfl_xor(hi, mask, 64);
    return ((unsigned long long)(unsigned)hi << 32) | (unsigned)lo;
}

__global__ __launch_bounds__(256)
void rvq_argmin_k(const float* __restrict__ emb, const float* __restrict__ q,
                  const float* __restrict__ cbT, const float* __restrict__ cbn,
                  int* __restrict__ codes, float* __restrict__ codes_out, int iq)
{
    const int n0 = blockIdx.x * 16;
    const int tid = threadIdx.x;
    __shared__ float res[16][256];
    for (int idx = tid; idx < 16 * 256; idx += 256) {
        int nl = idx >> 8, c = idx & 255;
        size_t g = (size_t)(n0 + nl) * 256 + c;
        res[nl][c] = emb[g] - q[g];
    }
    __syncthreads();
    float dot[16][4];
#pragma unroll
    for (int nl = 0; nl < 16; ++nl)
#pragma unroll
        for (int j = 0; j < 4; ++j) dot[nl][j] = 0.f;

    const float* cbtp = cbT + tid * 4;
    for (int c = 0; c < 256; ++c) {
        const float4 cbv = *(const float4*)(cbtp + (size_t)c * 1024);
#pragma unroll
        for (int nl = 0; nl < 16; ++nl) {
            const float r = res[nl][c];
            dot[nl][0] = fmaf(cbv.x, r, dot[nl][0]);
            dot[nl][1] = fmaf(cbv.y, r, dot[nl][1]);
            dot[nl][2] = fmaf(cbv.z, r, dot[nl][2]);
            dot[nl][3] = fmaf(cbv.w, r, dot[nl][3]);
        }
    }
    const float4 nrm = *(const float4*)(cbn + tid * 4);
    __shared__ unsigned long long wred[4][16];
    const int wave = tid >> 6, lane = tid & 63;
#pragma unroll
    for (int nl = 0; nl < 16; ++nl) {
        float s0 = nrm.x - 2.f * dot[nl][0];
        float s1 = nrm.y - 2.f * dot[nl][1];
        float s2 = nrm.z - 2.f * dot[nl][2];
        float s3 = nrm.w - 2.f * dot[nl][3];
        unsigned long long key =
            ((unsigned long long)ordbits(s0) << 32) | (unsigned)(tid * 4 + 0);
        unsigned long long k1 =
            ((unsigned long long)ordbits(s1) << 32) | (unsigned)(tid * 4 + 1);
        unsigned long long k2 =
            ((unsigned long long)ordbits(s2) << 32) | (unsigned)(tid * 4 + 2);
        unsigned long long k3 =
            ((unsigned long long)ordbits(s3) << 32) | (unsigned)(tid * 4 + 3);
        if (k1 < key) key = k1;
        if (k2 < key) key = k2;
        if (k3 < key) key = k3;
        for (int off = 32; off; off >>= 1) {
            unsigned long long o = shfl_xor_u64(key, off);
            if (o < key) key = o;
        }
        if (lane == 0) wred[wave][nl] = key;
    }
    __syncthreads();
    if (tid < 16) {
        unsigned long long bkey = wred[0][tid];
        if (wred[1][tid] < bkey) bkey = wred[1][tid];
        if (wred[2][tid] < bkey) bkey = wred[2][tid];
        if (wred[3][tid] < bkey) bkey = wred[3][tid];
        const int code = (int)(bkey & 0xffffffffull);
        codes[(size_t)(n0 + tid) * 8 + iq] = code;
        codes_out[(size_t)(n0 + tid) * 8 + iq] = (float)code;
    }
}

__global__ __launch_bounds__(256)
void rvq_update_k(const float* __restrict__ emb, float* __restrict__ q,
                  const float* __restrict__ cb, const int* __restrict__ codes,
                  float* __restrict__ commit, int iq)
{
    const int n = blockIdx.x, c = threadIdx.x;
    const int code = codes[(size_t)n * 8 + iq];
    const size_t g = (size_t)n * 256 + c;
    const float qv = q[g] + cb[(size_t)code * 256 + c];
    q[g] = qv;
    const float e = qv - emb[g];
    float s = e * e;
    for (int off = 32; off; off >>= 1) s += __shfl_down(s, off, 64);
    __shared__ float ls[4];
    if ((c & 63) == 0) ls[c >> 6] = s;
    __syncthreads();
    if (c == 0) atomicAdd(commit, ls[0] + ls[1] + ls[2] + ls[3]);
}

__global__ void commit_write_k(const float* __restrict__ commit, float* __restrict__ out)
{
    out[0] = commit[0] * (1.f / (4096.f * 256.f));
}

// ============================================================================
extern "C" void kernel_launch(void* const* d_in, const int* in_sizes, int n_in,
                              void* d_out, int out_size, void* d_ws, size_t ws_size,
                              hipStream_t stream)
{
    const float* x    = (const float*)d_in[0];
    const float* ed0w = (const float*)d_in[1];
    const float* ed0b = (const float*)d_in[2];
    const float* edw  = (const float*)d_in[3];
    const float* edb  = (const float*)d_in[4];
    const float* erw  = (const float*)d_in[5];
    const float* erb  = (const float*)d_in[6];
    const float* drw  = (const float*)d_in[7];
    const float* drb  = (const float*)d_in[8];
    const float* duw  = (const float*)d_in[9];
    const float* dub  = (const float*)d_in[10];
    const float* dulw = (const float*)d_in[11];
    const float* dulb = (const float*)d_in[12];
    const float* rsum = (const float*)d_in[13];
    const float* rusg = (const float*)d_in[14];
    float* out = (float*)d_out;

    char* base = (char*)d_ws;
    size_t o = 0;
    ushort_t* wH3 = (ushort_t*)(base + o); o += 31457280;   // 80*3*65536 bf16
    ushort_t* wL3 = (ushort_t*)(base + o); o += 31457280;
    ushort_t* w4H = (ushort_t*)(base + o); o += 4194304;    // 8*4*65536 bf16
    ushort_t* w4L = (ushort_t*)(base + o); o += 4194304;
    ushort_t* AH  = (ushort_t*)(base + o); o += 33554432;   // act [2][32768][256]
    ushort_t* AL  = (ushort_t*)(base + o); o += 33554432;
    ushort_t* BH  = (ushort_t*)(base + o); o += 33554432;
    ushort_t* BL  = (ushort_t*)(base + o); o += 33554432;
    float* emb    = (float*)(base + o);    o += 4194304;
    float* q      = (float*)(base + o);    o += 4194304;
    float* commit = (float*)(base + o);    o += 64;
    float* cb     = (float*)(base + o);    o += 1048576;
    float* cbT    = (float*)(base + o);    o += 1048576;
    float* cbn    = (float*)(base + o);    o += 4096;
    int*   codes  = (int*)(base + o);      o += 131072;

    static const int DIL[4] = {3, 9, 27, 81};

    hipMemsetAsync(q, 0, 4194304 + 64, stream);   // q + commit

    // weight prep
    wprep3_k<<<20480, 256, 0, stream>>>(erw, drw, wH3, wL3);
    wprep4_k<<<2048, 256, 0, stream>>>(edw, duw, w4H, w4L);

    // -------------------- encoder --------------------
    down0_k2<<<dim3(32768, 2), 256, 0, stream>>>(x, ed0w, ed0b, AH, AL);
    int L = 32768;
    for (int i = 0; i < 5; ++i) {
        if (i > 0) {
            const ushort_t* wh = w4H + (size_t)(i - 1) * 262144;
            const ushort_t* wl = w4L + (size_t)(i - 1) * 262144;
            convs_k<4, 2, false><<<dim3(L / 2 / 64, 1, 2), 256, 0, stream>>>(
                AH, AL, wh, wl, edb + (i - 1) * 256, AH, AL, 0.f, BH, BL, L, L / 2, 1, 1);
            ushort_t* t;
            t = AH; AH = BH; BH = t;
            t = AL; AL = BL; BL = t;
            L /= 2;
        }
        for (int j = 0; j < 4; ++j) {
            const int d = DIL[j];
            const size_t u = (size_t)(i * 4 + j) * 2;
            convs_k<3, 1, true><<<dim3(L / 64, 1, 2), 256, 0, stream>>>(
                AH, AL, wH3 + (u + 0) * 196608, wL3 + (u + 0) * 196608, erb + (u + 0) * 256,
                AH, AL, 0.f, BH, BL, L, L, d, d);
            convs_k<3, 1, true><<<dim3(L / 64, 1, 2), 256, 0, stream>>>(
                BH, BL, wH3 + (u + 1) * 196608, wL3 + (u + 1) * 196608, erb + (u + 1) * 256,
                AH, AL, 1.f, AH, AL, L, L, 1, 1);
        }
    }

    // -------------------- RVQ --------------------
    emb_k<<<4096, 256, 0, stream>>>(AH, AL, emb);
    for (int iq = 0; iq < 8; ++iq) {
        rvq_cb_k<<<1024, 256, 0, stream>>>(rsum, rusg, cb, cbT, cbn, iq);
        rvq_argmin_k<<<256, 256, 0, stream>>>(emb, q, cbT, cbn, codes, out + 131072, iq);
        rvq_update_k<<<4096, 256, 0, stream>>>(emb, q, cb, codes, commit, iq);
    }
    qsplit_k<<<4096, 256, 0, stream>>>(q, AH, AL);

    // -------------------- decoder --------------------
    L = 2048;
    for (int i = 0; i < 5; ++i) {
        for (int j = 0; j < 4; ++j) {
            const int d = DIL[j];
            // decoder conv slab indices are 40..79: conv = 40 + (i*4+j)*2 + {0,1}
            const size_t u = 40 + (size_t)(i * 4 + j) * 2;
            convs_k<3, 1, true><<<dim3(L / 64, 1, 2), 256, 0, stream>>>(
                AH, AL, wH3 + (u + 0) * 196608, wL3 + (u + 0) * 196608,
                drb + ((size_t)(i * 4 + j) * 2 + 0) * 256,
                AH, AL, 0.f, BH, BL, L, L, d, d);
            convs_k<3, 1, true><<<dim3(L / 64, 1, 2), 256, 0, stream>>>(
                BH, BL, wH3 + (u + 1) * 196608, wL3 + (u + 1) * 196608,
                drb + ((size_t)(i * 4 + j) * 2 + 1) * 256,
                AH, AL, 2.f, AH, AL, L, L, 1, 1);
        }
        if (i < 4) {
            const ushort_t* wh = w4H + (size_t)(4 + i) * 262144;
            const ushort_t* wl = w4L + (size_t)(4 + i) * 262144;
            convt_k<<<dim3(L / 64, 1, 2), 256, 0, stream>>>(
                AH, AL, wh, wl, dub + i * 256, BH, BL, L);
            ushort_t* t;
            t = AH; AH = BH; BH = t;
            t = AL; AL = BL; BL = t;
            L *= 2;
        } else {
            uplast_k2<<<dim3(L / 256, 2), 256, 0, stream>>>(AH, AL, dulw, dulb, out, L);
        }
    }

    commit_write_k<<<1, 1, 0, stream>>>(commit, out + 163840);
}

// Round 5
// 6714.284 us; speedup vs baseline: 3.2535x; 1.1340x over previous
//
#include <hip/hip_runtime.h>
#include <cstdint>

#define DEVFN static __device__ __forceinline__
typedef unsigned short ushort_t;
typedef unsigned int uint_t;
typedef short short8 __attribute__((ext_vector_type(8)));
typedef float f32x4 __attribute__((ext_vector_type(4)));

DEVFN float bf2f(ushort_t h) { return __uint_as_float(((uint_t)h) << 16); }
DEVFN ushort_t bfhi(float f) {
    uint_t u = __float_as_uint(f);
    u += 0x7fffu + ((u >> 16) & 1u);
    return (ushort_t)(u >> 16);
}
DEVFN void fsplit(float f, ushort_t& h, ushort_t& l) {
    h = bfhi(f);
    l = bfhi(f - bf2f(h));
}
// relu on a packed pair of bf16 hi/lo dwords (2 elements each)
DEVFN void relu_pair(uint_t& h, uint_t& l) {
    float f0 = bf2f((ushort_t)(h & 0xffffu)) + bf2f((ushort_t)(l & 0xffffu));
    float f1 = bf2f((ushort_t)(h >> 16)) + bf2f((ushort_t)(l >> 16));
    if (f0 <= 0.f) { h &= 0xffff0000u; l &= 0xffff0000u; }
    if (f1 <= 0.f) { h &= 0x0000ffffu; l &= 0x0000ffffu; }
}

// ============================================================================
// weight prep: fp32 [co][ci][k] -> bf16 hi/lo [tap][co][ci]
// ============================================================================
__global__ __launch_bounds__(256)
void wprep3_k(const float* __restrict__ erw, const float* __restrict__ drw,
              ushort_t* __restrict__ wH, ushort_t* __restrict__ wL)
{
    const int gid = blockIdx.x * 256 + threadIdx.x;   // 80*65536 threads
    const int conv = gid >> 16;
    const int rem  = gid & 65535;                      // co*256+ci
    const int co = rem >> 8, ci = rem & 255;
    const float* src = (conv < 40) ? (erw + (size_t)conv * 196608)
                                   : (drw + (size_t)(conv - 40) * 196608);
    const float* p = src + ((size_t)co * 256 + ci) * 3;
    ushort_t* oh = wH + (size_t)conv * 196608 + rem;
    ushort_t* ol = wL + (size_t)conv * 196608 + rem;
#pragma unroll
    for (int k = 0; k < 3; ++k) {
        ushort_t h, l; fsplit(p[k], h, l);
        oh[k * 65536] = h; ol[k * 65536] = l;
    }
}

__global__ __launch_bounds__(256)
void wprep4_k(const float* __restrict__ edw, const float* __restrict__ duw,
              ushort_t* __restrict__ wH, ushort_t* __restrict__ wL)
{
    const int gid = blockIdx.x * 256 + threadIdx.x;   // 8*65536 threads
    const int conv = gid >> 16;
    const int rem  = gid & 65535;
    const int co = rem >> 8, ci = rem & 255;
    ushort_t* oh = wH + (size_t)conv * 262144 + rem;
    ushort_t* ol = wL + (size_t)conv * 262144 + rem;
#pragma unroll
    for (int k = 0; k < 4; ++k) {
        float f;
        // edw: [conv][out][in][k]  (co = out)
        // duw: [conv][in][out][k]  -> element (out=co, in=ci) at (ci*256+co)*4+k
        if (conv < 4)  f = edw[(size_t)conv * 262144 + ((size_t)co * 256 + ci) * 4 + k];
        else           f = duw[(size_t)(conv - 4) * 262144 + ((size_t)ci * 256 + co) * 4 + k];
        ushort_t h, l; fsplit(f, h, l);
        oh[k * 65536] = h; ol[k * 65536] = l;
    }
}

// ============================================================================
// split-precision MFMA conv: out[b,to,co] = bias + sum_{tap,ci} W x  (+alpha*src)
// act layout [b][t][256c] bf16 hi/lo. Block: NT*16 t x 256 co, 4 waves x 64co.
// NT=8: 128 t-rows, 61 KB LDS, 2 blocks/CU (acc in AGPRs).
// NT=4: 64 t-rows, 50 KB LDS, 3 blocks/CU.
// ============================================================================
template<int TAPS, int STRIDE, bool RELU, int NT>
__global__ __launch_bounds__(256, (NT == 8) ? 2 : 3)
void convs_k(const ushort_t* __restrict__ inH, const ushort_t* __restrict__ inL,
             const ushort_t* __restrict__ wH, const ushort_t* __restrict__ wL,
             const float* __restrict__ bias,
             const ushort_t* __restrict__ srcH, const ushort_t* __restrict__ srcL,
             float alpha,
             ushort_t* __restrict__ outH, ushort_t* __restrict__ outL,
             int Lin, int Lout, int dil, int pad)
{
    constexpr int ROWS = NT * 16;
    constexpr int XSB = ROWS * 40 * 2;             // bytes per x buffer
    __shared__ __align__(16) char sarena[2 * XSB + 2 * 20480];
    ushort_t (*xsH)[40] = (ushort_t(*)[40])(sarena);
    ushort_t (*xsL)[40] = (ushort_t(*)[40])(sarena + XSB);
    ushort_t (*wsH)[40] = (ushort_t(*)[40])(sarena + 2 * XSB);
    ushort_t (*wsL)[40] = (ushort_t(*)[40])(sarena + 2 * XSB + 20480);

    const int tid = threadIdx.x;
    const int b = blockIdx.z;
    const int t0 = blockIdx.x * ROWS;
    const int wave = tid >> 6, lane = tid & 63;
    const int quad = lane >> 4, lr = lane & 15;
    const size_t inbase = (size_t)b * Lin * 256;

    f32x4 acc[4][NT];
#pragma unroll
    for (int m = 0; m < 4; ++m)
#pragma unroll
        for (int n = 0; n < NT; ++n) acc[m][n] = (f32x4)0.f;

    for (int tap = 0; tap < TAPS; ++tap) {
        const ushort_t* wHt = wH + (size_t)tap * 65536;
        const ushort_t* wLt = wL + (size_t)tap * 65536;
        for (int chunk = 0; chunk < 8; ++chunk) {
            const int ci0 = chunk * 32;
            __syncthreads();
            // ---- stage x tile: ROWS x 32 ci ----
#pragma unroll
            for (int rr = 0; rr < NT / 4; ++rr) {
                const int idx = rr * 256 + tid;
                const int r = idx >> 2, p = idx & 3;
                const int t = STRIDE * (t0 + r) - pad + tap * dil;
                uint4 hv = make_uint4(0, 0, 0, 0), lv = hv;
                if (t >= 0 && t < Lin) {
                    const size_t g = inbase + (size_t)t * 256 + ci0 + p * 8;
                    hv = *(const uint4*)(inH + g);
                    lv = *(const uint4*)(inL + g);
                    if (RELU) {
                        relu_pair(hv.x, lv.x); relu_pair(hv.y, lv.y);
                        relu_pair(hv.z, lv.z); relu_pair(hv.w, lv.w);
                    }
                }
                *(uint4*)&xsH[r][p * 8] = hv;
                *(uint4*)&xsL[r][p * 8] = lv;
            }
            // ---- stage W tile: 256 co x 32 ci ----
#pragma unroll
            for (int it = 0; it < 4; ++it) {
                const int idx = tid + 256 * it;
                const int co = idx >> 2, p = idx & 3;
                const size_t g = (size_t)co * 256 + ci0 + p * 8;
                *(uint4*)&wsH[co][p * 8] = *(const uint4*)(wHt + g);
                *(uint4*)&wsL[co][p * 8] = *(const uint4*)(wLt + g);
            }
            __syncthreads();
            // ---- compute ----
            const int cow = wave * 64;
            short8 aH[4], aL[4];
#pragma unroll
            for (int m = 0; m < 4; ++m) {
                aH[m] = *(const short8*)&wsH[cow + m * 16 + lr][quad * 8];
                aL[m] = *(const short8*)&wsL[cow + m * 16 + lr][quad * 8];
            }
#pragma unroll
            for (int n = 0; n < NT; ++n) {
                const short8 bH = *(const short8*)&xsH[n * 16 + lr][quad * 8];
                const short8 bL = *(const short8*)&xsL[n * 16 + lr][quad * 8];
#pragma unroll
                for (int m = 0; m < 4; ++m) {
                    acc[m][n] = __builtin_amdgcn_mfma_f32_16x16x32_bf16(aH[m], bH, acc[m][n], 0, 0, 0);
                    acc[m][n] = __builtin_amdgcn_mfma_f32_16x16x32_bf16(aH[m], bL, acc[m][n], 0, 0, 0);
                    acc[m][n] = __builtin_amdgcn_mfma_f32_16x16x32_bf16(aL[m], bH, acc[m][n], 0, 0, 0);
                }
            }
        }
    }
    // ---- coalesced epilogue (16 rows per n-group through LDS) ----
    float4 bvv[4];
    {
        const int cow = wave * 64;
#pragma unroll
        for (int m = 0; m < 4; ++m)
            bvv[m] = *(const float4*)&bias[cow + m * 16 + quad * 4];
    }
    __syncthreads();
    float (*ebuf)[260] = (float(*)[260])sarena;   // 16 rows x 260 cols
    const int cow = wave * 64;
#pragma unroll
    for (int n = 0; n < NT; ++n) {
#pragma unroll
        for (int m = 0; m < 4; ++m) {
            float4 v;
            v.x = acc[m][n][0] + bvv[m].x;
            v.y = acc[m][n][1] + bvv[m].y;
            v.z = acc[m][n][2] + bvv[m].z;
            v.w = acc[m][n][3] + bvv[m].w;
            *(float4*)&ebuf[lr][cow + m * 16 + quad * 4] = v;
        }
        __syncthreads();
        {
            const int row = tid >> 4;
            const int c00 = (tid & 15) * 4;
            const int t = t0 + n * 16 + row;
            const size_t gr = ((size_t)b * Lout + t) * 256;
#pragma unroll
            for (int rep = 0; rep < 4; ++rep) {
                const int col = c00 + rep * 64;
                float4 v = *(const float4*)&ebuf[row][col];
                if (alpha != 0.f) {
                    const ushort4 sh = *(const ushort4*)(srcH + gr + col);
                    const ushort4 sl = *(const ushort4*)(srcL + gr + col);
                    v.x += alpha * (bf2f(sh.x) + bf2f(sl.x));
                    v.y += alpha * (bf2f(sh.y) + bf2f(sl.y));
                    v.z += alpha * (bf2f(sh.z) + bf2f(sl.z));
                    v.w += alpha * (bf2f(sh.w) + bf2f(sl.w));
                }
                ushort4 oh, ol;
                fsplit(v.x, oh.x, ol.x); fsplit(v.y, oh.y, ol.y);
                fsplit(v.z, oh.z, ol.z); fsplit(v.w, oh.w, ol.w);
                *(ushort4*)(outH + gr + col) = oh;
                *(ushort4*)(outL + gr + col) = ol;
            }
        }
        __syncthreads();
    }
}

// ============================================================================
// conv transpose k=4 s=2 p=1 (split MFMA). Block: 64 input m x 256 co.
// out[2m]   = x[m]w1 + x[m-1]w3 ; out[2m+1] = x[m+1]w0 + x[m]w2
// tap loop MUST be unrolled: acc[..][ph] with runtime ph sends the whole
// accumulator array to scratch (R4: 1.17 GB writes/dispatch, VGPR=76).
// ============================================================================
__global__ __launch_bounds__(256, 2)
void convt_k(const ushort_t* __restrict__ inH, const ushort_t* __restrict__ inL,
             const ushort_t* __restrict__ wH, const ushort_t* __restrict__ wL,
             const float* __restrict__ bias,
             ushort_t* __restrict__ outH, ushort_t* __restrict__ outL, int Lin)
{
    __shared__ __align__(16) char sarena[51200];
    ushort_t (*xsH)[40] = (ushort_t(*)[40])(sarena);
    ushort_t (*xsL)[40] = (ushort_t(*)[40])(sarena + 5120);
    ushort_t (*wsH)[40] = (ushort_t(*)[40])(sarena + 10240);
    ushort_t (*wsL)[40] = (ushort_t(*)[40])(sarena + 30720);

    const int tid = threadIdx.x;
    const int b = blockIdx.z;
    const int m0 = blockIdx.x * 64;
    const int Lout = Lin * 2;
    const int wave = tid >> 6, lane = tid & 63;
    const int quad = lane >> 4, lr = lane & 15;
    const size_t inbase = (size_t)b * Lin * 256;

    f32x4 acc[4][4][2];
#pragma unroll
    for (int m = 0; m < 4; ++m)
#pragma unroll
        for (int n = 0; n < 4; ++n) { acc[m][n][0] = (f32x4)0.f; acc[m][n][1] = (f32x4)0.f; }

#pragma unroll
    for (int tap = 0; tap < 4; ++tap) {
        const int ph = (tap == 0 || tap == 2) ? 1 : 0;   // PHASE = {1,0,1,0}
        const int sh = (tap == 0) ? 1 : ((tap == 3) ? -1 : 0);  // SHIFT = {1,0,0,-1}
        const ushort_t* wHt = wH + (size_t)tap * 65536;
        const ushort_t* wLt = wL + (size_t)tap * 65536;
        for (int chunk = 0; chunk < 8; ++chunk) {
            const int ci0 = chunk * 32;
            __syncthreads();
            {
                const int r = tid >> 2, p = tid & 3;
                const int t = m0 + r + sh;
                uint4 hv = make_uint4(0, 0, 0, 0), lv = hv;
                if (t >= 0 && t < Lin) {
                    const size_t g = inbase + (size_t)t * 256 + ci0 + p * 8;
                    hv = *(const uint4*)(inH + g);
                    lv = *(const uint4*)(inL + g);
                }
                *(uint4*)&xsH[r][p * 8] = hv;
                *(uint4*)&xsL[r][p * 8] = lv;
            }
#pragma unroll
            for (int it = 0; it < 4; ++it) {
                const int idx = tid + 256 * it;
                const int co = idx >> 2, p = idx & 3;
                const size_t g = (size_t)co * 256 + ci0 + p * 8;
                *(uint4*)&wsH[co][p * 8] = *(const uint4*)(wHt + g);
                *(uint4*)&wsL[co][p * 8] = *(const uint4*)(wLt + g);
            }
            __syncthreads();
            const int cow = wave * 64;
            short8 aH[4], aL[4];
#pragma unroll
            for (int m = 0; m < 4; ++m) {
                aH[m] = *(const short8*)&wsH[cow + m * 16 + lr][quad * 8];
                aL[m] = *(const short8*)&wsL[cow + m * 16 + lr][quad * 8];
            }
#pragma unroll
            for (int n = 0; n < 4; ++n) {
                const short8 bH = *(const short8*)&xsH[n * 16 + lr][quad * 8];
                const short8 bL = *(const short8*)&xsL[n * 16 + lr][quad * 8];
#pragma unroll
                for (int m = 0; m < 4; ++m) {
                    acc[m][n][ph] = __builtin_amdgcn_mfma_f32_16x16x32_bf16(aH[m], bH, acc[m][n][ph], 0, 0, 0);
                    acc[m][n][ph] = __builtin_amdgcn_mfma_f32_16x16x32_bf16(aH[m], bL, acc[m][n][ph], 0, 0, 0);
                    acc[m][n][ph] = __builtin_amdgcn_mfma_f32_16x16x32_bf16(aL[m], bH, acc[m][n][ph], 0, 0, 0);
                }
            }
        }
    }
    // ---- coalesced epilogue: 32 output rows per n-group ----
    float4 bvv[4];
    {
        const int cow = wave * 64;
#pragma unroll
        for (int m = 0; m < 4; ++m)
            bvv[m] = *(const float4*)&bias[cow + m * 16 + quad * 4];
    }
    __syncthreads();
    float (*ebuf)[260] = (float(*)[260])sarena;   // 32 rows x 260 cols
    const int cow = wave * 64;
#pragma unroll
    for (int n = 0; n < 4; ++n) {
#pragma unroll
        for (int m = 0; m < 4; ++m) {
#pragma unroll
            for (int ph = 0; ph < 2; ++ph) {
                float4 v;
                v.x = acc[m][n][ph][0] + bvv[m].x;
                v.y = acc[m][n][ph][1] + bvv[m].y;
                v.z = acc[m][n][ph][2] + bvv[m].z;
                v.w = acc[m][n][ph][3] + bvv[m].w;
                *(float4*)&ebuf[2 * lr + ph][cow + m * 16 + quad * 4] = v;
            }
        }
        __syncthreads();
        {
            const int baset = 2 * (m0 + n * 16);
#pragma unroll
            for (int h = 0; h < 8; ++h) {
                const int row = (tid >> 4) + 16 * (h >> 2);
                const int col = (tid & 15) * 4 + (h & 3) * 64;
                const int t = baset + row;
                const size_t gr = ((size_t)b * Lout + t) * 256 + col;
                float4 v = *(const float4*)&ebuf[row][col];
                ushort4 oh, ol;
                fsplit(v.x, oh.x, ol.x); fsplit(v.y, oh.y, ol.y);
                fsplit(v.z, oh.z, ol.z); fsplit(v.w, oh.w, ol.w);
                *(ushort4*)(outH + gr) = oh;
                *(ushort4*)(outL + gr) = ol;
            }
        }
        __syncthreads();
    }
}

// ============================================================================
// first conv 1->256 k=4 s=2 p=1 ; writes [b][t][c] hi/lo
// ============================================================================
__global__ __launch_bounds__(256)
void down0_k2(const float* __restrict__ x, const float* __restrict__ w,
              const float* __restrict__ bias,
              ushort_t* __restrict__ outH, ushort_t* __restrict__ outL)
{
    const int t = blockIdx.x;               // 32768
    const int b = blockIdx.y;
    const int co = threadIdx.x;
    const float* xb = x + (size_t)b * 65536;
    const float4 wv = *(const float4*)(w + co * 4);
    float s = bias[co];
    const int ti0 = 2 * t - 1;
    if (ti0 >= 0)      s = fmaf(xb[ti0], wv.x, s);
    s = fmaf(xb[ti0 + 1], wv.y, s);
    s = fmaf(xb[ti0 + 2], wv.z, s);
    if (ti0 + 3 < 65536) s = fmaf(xb[ti0 + 3], wv.w, s);
    ushort_t h, l; fsplit(s, h, l);
    const size_t g = ((size_t)b * 32768 + t) * 256 + co;
    outH[g] = h; outL[g] = l;
}

// ============================================================================
// last conv transpose 256->1
// ============================================================================
__global__ __launch_bounds__(256)
void uplast_k2(const ushort_t* __restrict__ inH, const ushort_t* __restrict__ inL,
               const float* __restrict__ w, const float* __restrict__ bias,
               float* __restrict__ out, int Lin)
{
    const int m = blockIdx.x * 256 + threadIdx.x;
    const int b = blockIdx.y;
    const float bv = bias[0];
    float aE = bv, aO = bv;
    const size_t base = (size_t)b * Lin * 256;
    const ushort_t* r0H = inH + base + (size_t)m * 256;
    const ushort_t* r0L = inL + base + (size_t)m * 256;
    const bool hasM = (m > 0), hasP = (m + 1 < Lin);
    for (int c0 = 0; c0 < 256; c0 += 8) {
        uint4 h0 = *(const uint4*)(r0H + c0);
        uint4 l0 = *(const uint4*)(r0L + c0);
        uint4 hm = make_uint4(0,0,0,0), lm = hm, hp = hm, lp = hm;
        if (hasM) { hm = *(const uint4*)(r0H - 256 + c0); lm = *(const uint4*)(r0L - 256 + c0); }
        if (hasP) { hp = *(const uint4*)(r0H + 256 + c0); lp = *(const uint4*)(r0L + 256 + c0); }
        const uint_t* h0p = (const uint_t*)&h0; const uint_t* l0p = (const uint_t*)&l0;
        const uint_t* hmp = (const uint_t*)&hm; const uint_t* lmp = (const uint_t*)&lm;
        const uint_t* hpp = (const uint_t*)&hp; const uint_t* lpp = (const uint_t*)&lp;
#pragma unroll
        for (int e = 0; e < 4; ++e) {
#pragma unroll
            for (int half = 0; half < 2; ++half) {
                const int sh = half * 16;
                const int ci = c0 + e * 2 + half;
                const float x0  = bf2f((ushort_t)(h0p[e] >> sh)) + bf2f((ushort_t)(l0p[e] >> sh));
                const float xm1 = bf2f((ushort_t)(hmp[e] >> sh)) + bf2f((ushort_t)(lmp[e] >> sh));
                const float xp1 = bf2f((ushort_t)(hpp[e] >> sh)) + bf2f((ushort_t)(lpp[e] >> sh));
                const float4 wv = *(const float4*)(w + ci * 4);
                aE = fmaf(x0, wv.y, fmaf(xm1, wv.w, aE));
                aO = fmaf(xp1, wv.x, fmaf(x0, wv.z, aO));
            }
        }
    }
    *(float2*)(out + (size_t)b * 2 * Lin + 2 * m) = make_float2(aE, aO);
}

// ============================================================================
// act <-> fp32 emb/q
// ============================================================================
__global__ void emb_k(const ushort_t* __restrict__ H, const ushort_t* __restrict__ L,
                      float* __restrict__ emb)
{
    const size_t g = (size_t)blockIdx.x * 256 + threadIdx.x;
    emb[g] = bf2f(H[g]) + bf2f(L[g]);
}
__global__ void qsplit_k(const float* __restrict__ q,
                         ushort_t* __restrict__ H, ushort_t* __restrict__ L)
{
    const size_t g = (size_t)blockIdx.x * 256 + threadIdx.x;
    ushort_t h, l; fsplit(q[g], h, l);
    H[g] = h; L[g] = l;
}

// ============================================================================
// RVQ (fp32)
// ============================================================================
__global__ __launch_bounds__(256)
void rvq_cb_k(const float* __restrict__ sum, const float* __restrict__ usage,
              float* __restrict__ cb, float* __restrict__ cbT,
              float* __restrict__ cbn, int iq)
{
    const int k = blockIdx.x, c = threadIdx.x;
    const float den = fmaxf(usage[iq * 1024 + k], 1e-5f);
    const float v = sum[((size_t)iq * 1024 + k) * 256 + c] / den;
    cb[(size_t)k * 256 + c] = v;
    cbT[(size_t)c * 1024 + k] = v;
    float s = v * v;
    for (int off = 32; off; off >>= 1) s += __shfl_down(s, off, 64);
    __shared__ float ls[4];
    if ((c & 63) == 0) ls[c >> 6] = s;
    __syncthreads();
    if (c == 0) cbn[k] = ls[0] + ls[1] + ls[2] + ls[3];
}

DEVFN unsigned int ordbits(float f)
{
    unsigned u = __float_as_uint(f);
    return (u & 0x80000000u) ? ~u : (u | 0x80000000u);
}
DEVFN unsigned long long shfl_xor_u64(unsigned long long v, int mask)
{
    int lo = (int)(v & 0xffffffffull), hi = (int)(v >> 32);
    lo = __shfl_xor(lo, mask, 64);
    hi = __shfl_xor(hi, mask, 64);
    return ((unsigned long long)(unsigned)hi << 32) | (unsigned)lo;
}

__global__ __launch_bounds__(256)
void rvq_argmin_k(const float* __restrict__ emb, const float* __restrict__ q,
                  const float* __restrict__ cbT, const float* __restrict__ cbn,
                  int* __restrict__ codes, float* __restrict__ codes_out, int iq)
{
    const int n0 = blockIdx.x * 16;
    const int tid = threadIdx.x;
    __shared__ float res[16][256];
    for (int idx = tid; idx < 16 * 256; idx += 256) {
        int nl = idx >> 8, c = idx & 255;
        size_t g = (size_t)(n0 + nl) * 256 + c;
        res[nl][c] = emb[g] - q[g];
    }
    __syncthreads();
    float dot[16][4];
#pragma unroll
    for (int nl = 0; nl < 16; ++nl)
#pragma unroll
        for (int j = 0; j < 4; ++j) dot[nl][j] = 0.f;

    const float* cbtp = cbT + tid * 4;
    for (int c = 0; c < 256; ++c) {
        const float4 cbv = *(const float4*)(cbtp + (size_t)c * 1024);
#pragma unroll
        for (int nl = 0; nl < 16; ++nl) {
            const float r = res[nl][c];
            dot[nl][0] = fmaf(cbv.x, r, dot[nl][0]);
            dot[nl][1] = fmaf(cbv.y, r, dot[nl][1]);
            dot[nl][2] = fmaf(cbv.z, r, dot[nl][2]);
            dot[nl][3] = fmaf(cbv.w, r, dot[nl][3]);
        }
    }
    const float4 nrm = *(const float4*)(cbn + tid * 4);
    __shared__ unsigned long long wred[4][16];
    const int wave = tid >> 6, lane = tid & 63;
#pragma unroll
    for (int nl = 0; nl < 16; ++nl) {
        float s0 = nrm.x - 2.f * dot[nl][0];
        float s1 = nrm.y - 2.f * dot[nl][1];
        float s2 = nrm.z - 2.f * dot[nl][2];
        float s3 = nrm.w - 2.f * dot[nl][3];
        unsigned long long key =
            ((unsigned long long)ordbits(s0) << 32) | (unsigned)(tid * 4 + 0);
        unsigned long long k1 =
            ((unsigned long long)ordbits(s1) << 32) | (unsigned)(tid * 4 + 1);
        unsigned long long k2 =
            ((unsigned long long)ordbits(s2) << 32) | (unsigned)(tid * 4 + 2);
        unsigned long long k3 =
            ((unsigned long long)ordbits(s3) << 32) | (unsigned)(tid * 4 + 3);
        if (k1 < key) key = k1;
        if (k2 < key) key = k2;
        if (k3 < key) key = k3;
        for (int off = 32; off; off >>= 1) {
            unsigned long long o = shfl_xor_u64(key, off);
            if (o < key) key = o;
        }
        if (lane == 0) wred[wave][nl] = key;
    }
    __syncthreads();
    if (tid < 16) {
        unsigned long long bkey = wred[0][tid];
        if (wred[1][tid] < bkey) bkey = wred[1][tid];
        if (wred[2][tid] < bkey) bkey = wred[2][tid];
        if (wred[3][tid] < bkey) bkey = wred[3][tid];
        const int code = (int)(bkey & 0xffffffffull);
        codes[(size_t)(n0 + tid) * 8 + iq] = code;
        codes_out[(size_t)(n0 + tid) * 8 + iq] = (float)code;
    }
}

__global__ __launch_bounds__(256)
void rvq_update_k(const float* __restrict__ emb, float* __restrict__ q,
                  const float* __restrict__ cb, const int* __restrict__ codes,
                  float* __restrict__ commit, int iq)
{
    const int n = blockIdx.x, c = threadIdx.x;
    const int code = codes[(size_t)n * 8 + iq];
    const size_t g = (size_t)n * 256 + c;
    const float qv = q[g] + cb[(size_t)code * 256 + c];
    q[g] = qv;
    const float e = qv - emb[g];
    float s = e * e;
    for (int off = 32; off; off >>= 1) s += __shfl_down(s, off, 64);
    __shared__ float ls[4];
    if ((c & 63) == 0) ls[c >> 6] = s;
    __syncthreads();
    if (c == 0) atomicAdd(commit, ls[0] + ls[1] + ls[2] + ls[3]);
}

__global__ void commit_write_k(const float* __restrict__ commit, float* __restrict__ out)
{
    out[0] = commit[0] * (1.f / (4096.f * 256.f));
}

// ============================================================================
extern "C" void kernel_launch(void* const* d_in, const int* in_sizes, int n_in,
                              void* d_out, int out_size, void* d_ws, size_t ws_size,
                              hipStream_t stream)
{
    const float* x    = (const float*)d_in[0];
    const float* ed0w = (const float*)d_in[1];
    const float* ed0b = (const float*)d_in[2];
    const float* edw  = (const float*)d_in[3];
    const float* edb  = (const float*)d_in[4];
    const float* erw  = (const float*)d_in[5];
    const float* erb  = (const float*)d_in[6];
    const float* drw  = (const float*)d_in[7];
    const float* drb  = (const float*)d_in[8];
    const float* duw  = (const float*)d_in[9];
    const float* dub  = (const float*)d_in[10];
    const float* dulw = (const float*)d_in[11];
    const float* dulb = (const float*)d_in[12];
    const float* rsum = (const float*)d_in[13];
    const float* rusg = (const float*)d_in[14];
    float* out = (float*)d_out;

    char* base = (char*)d_ws;
    size_t o = 0;
    ushort_t* wH3 = (ushort_t*)(base + o); o += 31457280;   // 80*3*65536 bf16
    ushort_t* wL3 = (ushort_t*)(base + o); o += 31457280;
    ushort_t* w4H = (ushort_t*)(base + o); o += 4194304;    // 8*4*65536 bf16
    ushort_t* w4L = (ushort_t*)(base + o); o += 4194304;
    ushort_t* AH  = (ushort_t*)(base + o); o += 33554432;   // act [2][32768][256]
    ushort_t* AL  = (ushort_t*)(base + o); o += 33554432;
    ushort_t* BH  = (ushort_t*)(base + o); o += 33554432;
    ushort_t* BL  = (ushort_t*)(base + o); o += 33554432;
    float* emb    = (float*)(base + o);    o += 4194304;
    float* q      = (float*)(base + o);    o += 4194304;
    float* commit = (float*)(base + o);    o += 64;
    float* cb     = (float*)(base + o);    o += 1048576;
    float* cbT    = (float*)(base + o);    o += 1048576;
    float* cbn    = (float*)(base + o);    o += 4096;
    int*   codes  = (int*)(base + o);      o += 131072;

    static const int DIL[4] = {3, 9, 27, 81};

    hipMemsetAsync(q, 0, 4194304 + 64, stream);   // q + commit

    // weight prep
    wprep3_k<<<20480, 256, 0, stream>>>(erw, drw, wH3, wL3);
    wprep4_k<<<2048, 256, 0, stream>>>(edw, duw, w4H, w4L);

    // -------------------- encoder --------------------
    down0_k2<<<dim3(32768, 2), 256, 0, stream>>>(x, ed0w, ed0b, AH, AL);
    int L = 32768;
    for (int i = 0; i < 5; ++i) {
        if (i > 0) {
            const ushort_t* wh = w4H + (size_t)(i - 1) * 262144;
            const ushort_t* wl = w4L + (size_t)(i - 1) * 262144;
            const int Lout = L / 2;
            if (Lout >= 16384)
                convs_k<4, 2, false, 8><<<dim3(Lout / 128, 1, 2), 256, 0, stream>>>(
                    AH, AL, wh, wl, edb + (i - 1) * 256, AH, AL, 0.f, BH, BL, L, Lout, 1, 1);
            else
                convs_k<4, 2, false, 4><<<dim3(Lout / 64, 1, 2), 256, 0, stream>>>(
                    AH, AL, wh, wl, edb + (i - 1) * 256, AH, AL, 0.f, BH, BL, L, Lout, 1, 1);
            ushort_t* t;
            t = AH; AH = BH; BH = t;
            t = AL; AL = BL; BL = t;
            L = Lout;
        }
        for (int j = 0; j < 4; ++j) {
            const int d = DIL[j];
            const size_t u = (size_t)(i * 4 + j) * 2;
            const ushort_t* w0h = wH3 + (u + 0) * 196608;
            const ushort_t* w0l = wL3 + (u + 0) * 196608;
            const ushort_t* w1h = wH3 + (u + 1) * 196608;
            const ushort_t* w1l = wL3 + (u + 1) * 196608;
            const float* b0 = erb + (u + 0) * 256;
            const float* b1 = erb + (u + 1) * 256;
            if (L >= 16384) {
                convs_k<3, 1, true, 8><<<dim3(L / 128, 1, 2), 256, 0, stream>>>(
                    AH, AL, w0h, w0l, b0, AH, AL, 0.f, BH, BL, L, L, d, d);
                convs_k<3, 1, true, 8><<<dim3(L / 128, 1, 2), 256, 0, stream>>>(
                    BH, BL, w1h, w1l, b1, AH, AL, 1.f, AH, AL, L, L, 1, 1);
            } else {
                convs_k<3, 1, true, 4><<<dim3(L / 64, 1, 2), 256, 0, stream>>>(
                    AH, AL, w0h, w0l, b0, AH, AL, 0.f, BH, BL, L, L, d, d);
                convs_k<3, 1, true, 4><<<dim3(L / 64, 1, 2), 256, 0, stream>>>(
                    BH, BL, w1h, w1l, b1, AH, AL, 1.f, AH, AL, L, L, 1, 1);
            }
        }
    }

    // -------------------- RVQ --------------------
    emb_k<<<4096, 256, 0, stream>>>(AH, AL, emb);
    for (int iq = 0; iq < 8; ++iq) {
        rvq_cb_k<<<1024, 256, 0, stream>>>(rsum, rusg, cb, cbT, cbn, iq);
        rvq_argmin_k<<<256, 256, 0, stream>>>(emb, q, cbT, cbn, codes, out + 131072, iq);
        rvq_update_k<<<4096, 256, 0, stream>>>(emb, q, cb, codes, commit, iq);
    }
    qsplit_k<<<4096, 256, 0, stream>>>(q, AH, AL);

    // -------------------- decoder --------------------
    L = 2048;
    for (int i = 0; i < 5; ++i) {
        for (int j = 0; j < 4; ++j) {
            const int d = DIL[j];
            // decoder conv slab indices are 40..79: conv = 40 + (i*4+j)*2 + {0,1}
            const size_t u = 40 + (size_t)(i * 4 + j) * 2;
            const ushort_t* w0h = wH3 + (u + 0) * 196608;
            const ushort_t* w0l = wL3 + (u + 0) * 196608;
            const ushort_t* w1h = wH3 + (u + 1) * 196608;
            const ushort_t* w1l = wL3 + (u + 1) * 196608;
            const float* b0 = drb + ((size_t)(i * 4 + j) * 2 + 0) * 256;
            const float* b1 = drb + ((size_t)(i * 4 + j) * 2 + 1) * 256;
            if (L >= 16384) {
                convs_k<3, 1, true, 8><<<dim3(L / 128, 1, 2), 256, 0, stream>>>(
                    AH, AL, w0h, w0l, b0, AH, AL, 0.f, BH, BL, L, L, d, d);
                convs_k<3, 1, true, 8><<<dim3(L / 128, 1, 2), 256, 0, stream>>>(
                    BH, BL, w1h, w1l, b1, AH, AL, 2.f, AH, AL, L, L, 1, 1);
            } else {
                convs_k<3, 1, true, 4><<<dim3(L / 64, 1, 2), 256, 0, stream>>>(
                    AH, AL, w0h, w0l, b0, AH, AL, 0.f, BH, BL, L, L, d, d);
                convs_k<3, 1, true, 4><<<dim3(L / 64, 1, 2), 256, 0, stream>>>(
                    BH, BL, w1h, w1l, b1, AH, AL, 2.f, AH, AL, L, L, 1, 1);
            }
        }
        if (i < 4) {
            const ushort_t* wh = w4H + (size_t)(4 + i) * 262144;
            const ushort_t* wl = w4L + (size_t)(4 + i) * 262144;
            convt_k<<<dim3(L / 64, 1, 2), 256, 0, stream>>>(
                AH, AL, wh, wl, dub + i * 256, BH, BL, L);
            ushort_t* t;
            t = AH; AH = BH; BH = t;
            t = AL; AL = BL; BL = t;
            L *= 2;
        } else {
            uplast_k2<<<dim3(L / 256, 2), 256, 0, stream>>>(AH, AL, dulw, dulb, out, L);
        }
    }

    commit_write_k<<<1, 1, 0, stream>>>(commit, out + 163840);
}

// Round 6
// 6101.989 us; speedup vs baseline: 3.5799x; 1.1003x over previous
//
#include <hip/hip_runtime.h>
#include <cstdint>

#define DEVFN static __device__ __forceinline__
typedef unsigned short ushort_t;
typedef unsigned int uint_t;
typedef short short8 __attribute__((ext_vector_type(8)));
typedef float f32x4 __attribute__((ext_vector_type(4)));

DEVFN float bf2f(ushort_t h) { return __uint_as_float(((uint_t)h) << 16); }
DEVFN ushort_t bfhi(float f) {
    uint_t u = __float_as_uint(f);
    u += 0x7fffu + ((u >> 16) & 1u);
    return (ushort_t)(u >> 16);
}
DEVFN void fsplit(float f, ushort_t& h, ushort_t& l) {
    h = bfhi(f);
    l = bfhi(f - bf2f(h));
}
// relu on a packed pair of bf16 hi/lo dwords (2 elements each)
DEVFN void relu_pair(uint_t& h, uint_t& l) {
    float f0 = bf2f((ushort_t)(h & 0xffffu)) + bf2f((ushort_t)(l & 0xffffu));
    float f1 = bf2f((ushort_t)(h >> 16)) + bf2f((ushort_t)(l >> 16));
    if (f0 <= 0.f) { h &= 0xffff0000u; l &= 0xffff0000u; }
    if (f1 <= 0.f) { h &= 0x0000ffffu; l &= 0x0000ffffu; }
}

// ============================================================================
// weight prep: fp32 [co][ci][k] -> bf16 hi/lo [tap][co][ci]
// ============================================================================
__global__ __launch_bounds__(256)
void wprep3_k(const float* __restrict__ erw, const float* __restrict__ drw,
              ushort_t* __restrict__ wH, ushort_t* __restrict__ wL)
{
    const int gid = blockIdx.x * 256 + threadIdx.x;   // 80*65536 threads
    const int conv = gid >> 16;
    const int rem  = gid & 65535;                      // co*256+ci
    const int co = rem >> 8, ci = rem & 255;
    const float* src = (conv < 40) ? (erw + (size_t)conv * 196608)
                                   : (drw + (size_t)(conv - 40) * 196608);
    const float* p = src + ((size_t)co * 256 + ci) * 3;
    ushort_t* oh = wH + (size_t)conv * 196608 + rem;
    ushort_t* ol = wL + (size_t)conv * 196608 + rem;
#pragma unroll
    for (int k = 0; k < 3; ++k) {
        ushort_t h, l; fsplit(p[k], h, l);
        oh[k * 65536] = h; ol[k * 65536] = l;
    }
}

__global__ __launch_bounds__(256)
void wprep4_k(const float* __restrict__ edw, const float* __restrict__ duw,
              ushort_t* __restrict__ wH, ushort_t* __restrict__ wL)
{
    const int gid = blockIdx.x * 256 + threadIdx.x;   // 8*65536 threads
    const int conv = gid >> 16;
    const int rem  = gid & 65535;
    const int co = rem >> 8, ci = rem & 255;
    ushort_t* oh = wH + (size_t)conv * 262144 + rem;
    ushort_t* ol = wL + (size_t)conv * 262144 + rem;
#pragma unroll
    for (int k = 0; k < 4; ++k) {
        float f;
        if (conv < 4)  f = edw[(size_t)conv * 262144 + ((size_t)co * 256 + ci) * 4 + k];
        else           f = duw[(size_t)(conv - 4) * 262144 + ((size_t)ci * 256 + co) * 4 + k];
        ushort_t h, l; fsplit(f, h, l);
        oh[k * 65536] = h; ol[k * 65536] = l;
    }
}

// ============================================================================
// split-precision MFMA conv.
// act layout [b][t][256c] bf16 hi/lo. Block: NT*16 t x 256 co, 4 waves x 64co.
// x halo staged ONCE per ci-chunk (all taps); A-fragments read directly from
// global (16B/lane contiguous in [tap][co][ci] slab; L1/L2-served).
// ============================================================================
template<int TAPS, int STRIDE, bool RELU, int NT, int DMAX>
__global__ __launch_bounds__(256, (NT >= 8) ? 2 : 3)
void convs_k(const ushort_t* __restrict__ inH, const ushort_t* __restrict__ inL,
             const ushort_t* __restrict__ wH, const ushort_t* __restrict__ wL,
             const float* __restrict__ bias,
             const ushort_t* __restrict__ srcH, const ushort_t* __restrict__ srcL,
             float alpha,
             ushort_t* __restrict__ outH, ushort_t* __restrict__ outL,
             int Lin, int Lout, int dil, int pad)
{
    constexpr int ROWS = NT * 16;
    constexpr int SMAX = STRIDE * (ROWS - 1) + (TAPS - 1) * DMAX + 1;
    constexpr int XSB  = SMAX * 40 * 2;      // bytes per plane
    constexpr int ARENA = (2 * XSB > 16640) ? 2 * XSB : 16640;
    __shared__ __align__(16) char sarena[ARENA];
    ushort_t (*xsH)[40] = (ushort_t(*)[40])(sarena);
    ushort_t (*xsL)[40] = (ushort_t(*)[40])(sarena + XSB);

    const int tid = threadIdx.x;
    const int b = blockIdx.z;
    const int t0 = blockIdx.x * ROWS;
    const int wave = tid >> 6, lane = tid & 63;
    const int quad = lane >> 4, lr = lane & 15;
    const int cow = wave * 64;
    const size_t inbase = (size_t)b * Lin * 256;
    const int S = STRIDE * (ROWS - 1) + (TAPS - 1) * dil + 1;
    const int g0 = STRIDE * t0 - pad;

    f32x4 acc[4][NT];
#pragma unroll
    for (int m = 0; m < 4; ++m)
#pragma unroll
        for (int n = 0; n < NT; ++n) acc[m][n] = (f32x4)0.f;

    for (int chunk = 0; chunk < 8; ++chunk) {
        const int ci0 = chunk * 32;
        __syncthreads();
        // ---- stage x halo: S rows x 32 ci (once, all taps) ----
        for (int idx = tid; idx < S * 4; idx += 256) {
            const int s = idx >> 2, p = idx & 3;
            const int t = g0 + s;
            uint4 hv = make_uint4(0, 0, 0, 0), lv = hv;
            if (t >= 0 && t < Lin) {
                const size_t g = inbase + (size_t)t * 256 + ci0 + p * 8;
                hv = *(const uint4*)(inH + g);
                lv = *(const uint4*)(inL + g);
                if (RELU) {
                    relu_pair(hv.x, lv.x); relu_pair(hv.y, lv.y);
                    relu_pair(hv.z, lv.z); relu_pair(hv.w, lv.w);
                }
            }
            *(uint4*)&xsH[s][p * 8] = hv;
            *(uint4*)&xsL[s][p * 8] = lv;
        }
        __syncthreads();
        // ---- compute: taps inner, A from global ----
#pragma unroll
        for (int tap = 0; tap < TAPS; ++tap) {
            const ushort_t* wHt = wH + (size_t)tap * 65536 + ci0 + quad * 8;
            const ushort_t* wLt = wL + (size_t)tap * 65536 + ci0 + quad * 8;
            short8 aH[4], aL[4];
#pragma unroll
            for (int m = 0; m < 4; ++m) {
                const int co = cow + m * 16 + lr;
                aH[m] = *(const short8*)(wHt + co * 256);
                aL[m] = *(const short8*)(wLt + co * 256);
            }
            const int rb = tap * dil;
#pragma unroll
            for (int n = 0; n < NT; ++n) {
                const int srow = STRIDE * (n * 16 + lr) + rb;
                const short8 bH = *(const short8*)&xsH[srow][quad * 8];
                const short8 bL = *(const short8*)&xsL[srow][quad * 8];
#pragma unroll
                for (int m = 0; m < 4; ++m)
                    acc[m][n] = __builtin_amdgcn_mfma_f32_16x16x32_bf16(aH[m], bH, acc[m][n], 0, 0, 0);
#pragma unroll
                for (int m = 0; m < 4; ++m)
                    acc[m][n] = __builtin_amdgcn_mfma_f32_16x16x32_bf16(aH[m], bL, acc[m][n], 0, 0, 0);
#pragma unroll
                for (int m = 0; m < 4; ++m)
                    acc[m][n] = __builtin_amdgcn_mfma_f32_16x16x32_bf16(aL[m], bH, acc[m][n], 0, 0, 0);
            }
        }
    }
    // ---- coalesced epilogue (16 rows per n-group through LDS) ----
    float4 bvv[4];
#pragma unroll
    for (int m = 0; m < 4; ++m)
        bvv[m] = *(const float4*)&bias[cow + m * 16 + quad * 4];
    __syncthreads();
    float (*ebuf)[260] = (float(*)[260])sarena;   // 16 rows x 260 cols
#pragma unroll
    for (int n = 0; n < NT; ++n) {
#pragma unroll
        for (int m = 0; m < 4; ++m) {
            float4 v;
            v.x = acc[m][n][0] + bvv[m].x;
            v.y = acc[m][n][1] + bvv[m].y;
            v.z = acc[m][n][2] + bvv[m].z;
            v.w = acc[m][n][3] + bvv[m].w;
            *(float4*)&ebuf[lr][cow + m * 16 + quad * 4] = v;
        }
        __syncthreads();
        {
            const int row = tid >> 4;
            const int c00 = (tid & 15) * 4;
            const int t = t0 + n * 16 + row;
            const size_t gr = ((size_t)b * Lout + t) * 256;
#pragma unroll
            for (int rep = 0; rep < 4; ++rep) {
                const int col = c00 + rep * 64;
                float4 v = *(const float4*)&ebuf[row][col];
                if (alpha != 0.f) {
                    const ushort4 sh = *(const ushort4*)(srcH + gr + col);
                    const ushort4 sl = *(const ushort4*)(srcL + gr + col);
                    v.x += alpha * (bf2f(sh.x) + bf2f(sl.x));
                    v.y += alpha * (bf2f(sh.y) + bf2f(sl.y));
                    v.z += alpha * (bf2f(sh.z) + bf2f(sl.z));
                    v.w += alpha * (bf2f(sh.w) + bf2f(sl.w));
                }
                ushort4 oh, ol;
                fsplit(v.x, oh.x, ol.x); fsplit(v.y, oh.y, ol.y);
                fsplit(v.z, oh.z, ol.z); fsplit(v.w, oh.w, ol.w);
                *(ushort4*)(outH + gr + col) = oh;
                *(ushort4*)(outL + gr + col) = ol;
            }
        }
        __syncthreads();
    }
}

// ============================================================================
// conv transpose k=4 s=2 p=1 (split MFMA). Block: NTc*16 input m x 256 co.
// out[2m]   = x[m]w1 + x[m-1]w3 ; out[2m+1] = x[m+1]w0 + x[m]w2
// x halo staged once per chunk; A from global; taps fully unrolled
// (runtime-indexed acc goes to scratch — R4 lesson).
// ============================================================================
template<int NTc>
__global__ __launch_bounds__(256, 2)
void convt_k(const ushort_t* __restrict__ inH, const ushort_t* __restrict__ inL,
             const ushort_t* __restrict__ wH, const ushort_t* __restrict__ wL,
             const float* __restrict__ bias,
             ushort_t* __restrict__ outH, ushort_t* __restrict__ outL, int Lin)
{
    constexpr int ROWS = NTc * 16;
    constexpr int S = ROWS + 2;
    constexpr int XSB = S * 40 * 2;
    constexpr int ARENA = (2 * XSB > 33280) ? 2 * XSB : 33280;
    __shared__ __align__(16) char sarena[ARENA];
    ushort_t (*xsH)[40] = (ushort_t(*)[40])(sarena);
    ushort_t (*xsL)[40] = (ushort_t(*)[40])(sarena + XSB);

    const int tid = threadIdx.x;
    const int b = blockIdx.z;
    const int m0 = blockIdx.x * ROWS;
    const int Lout = Lin * 2;
    const int wave = tid >> 6, lane = tid & 63;
    const int quad = lane >> 4, lr = lane & 15;
    const int cow = wave * 64;
    const size_t inbase = (size_t)b * Lin * 256;

    f32x4 acc[4][NTc][2];
#pragma unroll
    for (int m = 0; m < 4; ++m)
#pragma unroll
        for (int n = 0; n < NTc; ++n) { acc[m][n][0] = (f32x4)0.f; acc[m][n][1] = (f32x4)0.f; }

    for (int chunk = 0; chunk < 8; ++chunk) {
        const int ci0 = chunk * 32;
        __syncthreads();
        for (int idx = tid; idx < S * 4; idx += 256) {
            const int s = idx >> 2, p = idx & 3;
            const int t = m0 - 1 + s;
            uint4 hv = make_uint4(0, 0, 0, 0), lv = hv;
            if (t >= 0 && t < Lin) {
                const size_t g = inbase + (size_t)t * 256 + ci0 + p * 8;
                hv = *(const uint4*)(inH + g);
                lv = *(const uint4*)(inL + g);
            }
            *(uint4*)&xsH[s][p * 8] = hv;
            *(uint4*)&xsL[s][p * 8] = lv;
        }
        __syncthreads();
#pragma unroll
        for (int tap = 0; tap < 4; ++tap) {
            const int ph = (tap == 0 || tap == 2) ? 1 : 0;   // PHASE = {1,0,1,0}
            const int sh = (tap == 0) ? 1 : ((tap == 3) ? -1 : 0);  // SHIFT
            const ushort_t* wHt = wH + (size_t)tap * 65536 + ci0 + quad * 8;
            const ushort_t* wLt = wL + (size_t)tap * 65536 + ci0 + quad * 8;
            short8 aH[4], aL[4];
#pragma unroll
            for (int m = 0; m < 4; ++m) {
                const int co = cow + m * 16 + lr;
                aH[m] = *(const short8*)(wHt + co * 256);
                aL[m] = *(const short8*)(wLt + co * 256);
            }
#pragma unroll
            for (int n = 0; n < NTc; ++n) {
                const int srow = n * 16 + lr + sh + 1;
                const short8 bH = *(const short8*)&xsH[srow][quad * 8];
                const short8 bL = *(const short8*)&xsL[srow][quad * 8];
#pragma unroll
                for (int m = 0; m < 4; ++m)
                    acc[m][n][ph] = __builtin_amdgcn_mfma_f32_16x16x32_bf16(aH[m], bH, acc[m][n][ph], 0, 0, 0);
#pragma unroll
                for (int m = 0; m < 4; ++m)
                    acc[m][n][ph] = __builtin_amdgcn_mfma_f32_16x16x32_bf16(aH[m], bL, acc[m][n][ph], 0, 0, 0);
#pragma unroll
                for (int m = 0; m < 4; ++m)
                    acc[m][n][ph] = __builtin_amdgcn_mfma_f32_16x16x32_bf16(aL[m], bH, acc[m][n][ph], 0, 0, 0);
            }
        }
    }
    // ---- coalesced epilogue: 32 output rows per n-group ----
    float4 bvv[4];
#pragma unroll
    for (int m = 0; m < 4; ++m)
        bvv[m] = *(const float4*)&bias[cow + m * 16 + quad * 4];
    __syncthreads();
    float (*ebuf)[260] = (float(*)[260])sarena;   // 32 rows x 260 cols
#pragma unroll
    for (int n = 0; n < NTc; ++n) {
#pragma unroll
        for (int m = 0; m < 4; ++m) {
#pragma unroll
            for (int ph = 0; ph < 2; ++ph) {
                float4 v;
                v.x = acc[m][n][ph][0] + bvv[m].x;
                v.y = acc[m][n][ph][1] + bvv[m].y;
                v.z = acc[m][n][ph][2] + bvv[m].z;
                v.w = acc[m][n][ph][3] + bvv[m].w;
                *(float4*)&ebuf[2 * lr + ph][cow + m * 16 + quad * 4] = v;
            }
        }
        __syncthreads();
        {
            const int baset = 2 * (m0 + n * 16);
#pragma unroll
            for (int h = 0; h < 8; ++h) {
                const int row = (tid >> 4) + 16 * (h >> 2);
                const int col = (tid & 15) * 4 + (h & 3) * 64;
                const int t = baset + row;
                const size_t gr = ((size_t)b * Lout + t) * 256 + col;
                float4 v = *(const float4*)&ebuf[row][col];
                ushort4 oh, ol;
                fsplit(v.x, oh.x, ol.x); fsplit(v.y, oh.y, ol.y);
                fsplit(v.z, oh.z, ol.z); fsplit(v.w, oh.w, ol.w);
                *(ushort4*)(outH + gr) = oh;
                *(ushort4*)(outL + gr) = ol;
            }
        }
        __syncthreads();
    }
}

// ============================================================================
// first conv 1->256 k=4 s=2 p=1 ; writes [b][t][c] hi/lo
// ============================================================================
__global__ __launch_bounds__(256)
void down0_k2(const float* __restrict__ x, const float* __restrict__ w,
              const float* __restrict__ bias,
              ushort_t* __restrict__ outH, ushort_t* __restrict__ outL)
{
    const int t = blockIdx.x;               // 32768
    const int b = blockIdx.y;
    const int co = threadIdx.x;
    const float* xb = x + (size_t)b * 65536;
    const float4 wv = *(const float4*)(w + co * 4);
    float s = bias[co];
    const int ti0 = 2 * t - 1;
    if (ti0 >= 0)      s = fmaf(xb[ti0], wv.x, s);
    s = fmaf(xb[ti0 + 1], wv.y, s);
    s = fmaf(xb[ti0 + 2], wv.z, s);
    if (ti0 + 3 < 65536) s = fmaf(xb[ti0 + 3], wv.w, s);
    ushort_t h, l; fsplit(s, h, l);
    const size_t g = ((size_t)b * 32768 + t) * 256 + co;
    outH[g] = h; outL[g] = l;
}

// ============================================================================
// last conv transpose 256->1
// ============================================================================
__global__ __launch_bounds__(256)
void uplast_k2(const ushort_t* __restrict__ inH, const ushort_t* __restrict__ inL,
               const float* __restrict__ w, const float* __restrict__ bias,
               float* __restrict__ out, int Lin)
{
    const int m = blockIdx.x * 256 + threadIdx.x;
    const int b = blockIdx.y;
    const float bv = bias[0];
    float aE = bv, aO = bv;
    const size_t base = (size_t)b * Lin * 256;
    const ushort_t* r0H = inH + base + (size_t)m * 256;
    const ushort_t* r0L = inL + base + (size_t)m * 256;
    const bool hasM = (m > 0), hasP = (m + 1 < Lin);
    for (int c0 = 0; c0 < 256; c0 += 8) {
        uint4 h0 = *(const uint4*)(r0H + c0);
        uint4 l0 = *(const uint4*)(r0L + c0);
        uint4 hm = make_uint4(0,0,0,0), lm = hm, hp = hm, lp = hm;
        if (hasM) { hm = *(const uint4*)(r0H - 256 + c0); lm = *(const uint4*)(r0L - 256 + c0); }
        if (hasP) { hp = *(const uint4*)(r0H + 256 + c0); lp = *(const uint4*)(r0L + 256 + c0); }
        const uint_t* h0p = (const uint_t*)&h0; const uint_t* l0p = (const uint_t*)&l0;
        const uint_t* hmp = (const uint_t*)&hm; const uint_t* lmp = (const uint_t*)&lm;
        const uint_t* hpp = (const uint_t*)&hp; const uint_t* lpp = (const uint_t*)&lp;
#pragma unroll
        for (int e = 0; e < 4; ++e) {
#pragma unroll
            for (int half = 0; half < 2; ++half) {
                const int sh = half * 16;
                const int ci = c0 + e * 2 + half;
                const float x0  = bf2f((ushort_t)(h0p[e] >> sh)) + bf2f((ushort_t)(l0p[e] >> sh));
                const float xm1 = bf2f((ushort_t)(hmp[e] >> sh)) + bf2f((ushort_t)(lmp[e] >> sh));
                const float xp1 = bf2f((ushort_t)(hpp[e] >> sh)) + bf2f((ushort_t)(lpp[e] >> sh));
                const float4 wv = *(const float4*)(w + ci * 4);
                aE = fmaf(x0, wv.y, fmaf(xm1, wv.w, aE));
                aO = fmaf(xp1, wv.x, fmaf(x0, wv.z, aO));
            }
        }
    }
    *(float2*)(out + (size_t)b * 2 * Lin + 2 * m) = make_float2(aE, aO);
}

// ============================================================================
// act <-> fp32 emb/q
// ============================================================================
__global__ void emb_k(const ushort_t* __restrict__ H, const ushort_t* __restrict__ L,
                      float* __restrict__ emb)
{
    const size_t g = (size_t)blockIdx.x * 256 + threadIdx.x;
    emb[g] = bf2f(H[g]) + bf2f(L[g]);
}
__global__ void qsplit_k(const float* __restrict__ q,
                         ushort_t* __restrict__ H, ushort_t* __restrict__ L)
{
    const size_t g = (size_t)blockIdx.x * 256 + threadIdx.x;
    ushort_t h, l; fsplit(q[g], h, l);
    H[g] = h; L[g] = l;
}

// ============================================================================
// RVQ (fp32)
// ============================================================================
__global__ __launch_bounds__(256)
void rvq_cb_k(const float* __restrict__ sum, const float* __restrict__ usage,
              float* __restrict__ cb, float* __restrict__ cbT,
              float* __restrict__ cbn, int iq)
{
    const int k = blockIdx.x, c = threadIdx.x;
    const float den = fmaxf(usage[iq * 1024 + k], 1e-5f);
    const float v = sum[((size_t)iq * 1024 + k) * 256 + c] / den;
    cb[(size_t)k * 256 + c] = v;
    cbT[(size_t)c * 1024 + k] = v;
    float s = v * v;
    for (int off = 32; off; off >>= 1) s += __shfl_down(s, off, 64);
    __shared__ float ls[4];
    if ((c & 63) == 0) ls[c >> 6] = s;
    __syncthreads();
    if (c == 0) cbn[k] = ls[0] + ls[1] + ls[2] + ls[3];
}

DEVFN unsigned int ordbits(float f)
{
    unsigned u = __float_as_uint(f);
    return (u & 0x80000000u) ? ~u : (u | 0x80000000u);
}
DEVFN unsigned long long shfl_xor_u64(unsigned long long v, int mask)
{
    int lo = (int)(v & 0xffffffffull), hi = (int)(v >> 32);
    lo = __shfl_xor(lo, mask, 64);
    hi = __shfl_xor(hi, mask, 64);
    return ((unsigned long long)(unsigned)hi << 32) | (unsigned)lo;
}

__global__ __launch_bounds__(256)
void rvq_argmin_k(const float* __restrict__ emb, const float* __restrict__ q,
                  const float* __restrict__ cbT, const float* __restrict__ cbn,
                  int* __restrict__ codes, float* __restrict__ codes_out, int iq)
{
    const int n0 = blockIdx.x * 16;
    const int tid = threadIdx.x;
    __shared__ float res[16][256];
    for (int idx = tid; idx < 16 * 256; idx += 256) {
        int nl = idx >> 8, c = idx & 255;
        size_t g = (size_t)(n0 + nl) * 256 + c;
        res[nl][c] = emb[g] - q[g];
    }
    __syncthreads();
    float dot[16][4];
#pragma unroll
    for (int nl = 0; nl < 16; ++nl)
#pragma unroll
        for (int j = 0; j < 4; ++j) dot[nl][j] = 0.f;

    const float* cbtp = cbT + tid * 4;
    for (int c = 0; c < 256; ++c) {
        const float4 cbv = *(const float4*)(cbtp + (size_t)c * 1024);
#pragma unroll
        for (int nl = 0; nl < 16; ++nl) {
            const float r = res[nl][c];
            dot[nl][0] = fmaf(cbv.x, r, dot[nl][0]);
            dot[nl][1] = fmaf(cbv.y, r, dot[nl][1]);
            dot[nl][2] = fmaf(cbv.z, r, dot[nl][2]);
            dot[nl][3] = fmaf(cbv.w, r, dot[nl][3]);
        }
    }
    const float4 nrm = *(const float4*)(cbn + tid * 4);
    __shared__ unsigned long long wred[4][16];
    const int wave = tid >> 6, lane = tid & 63;
#pragma unroll
    for (int nl = 0; nl < 16; ++nl) {
        float s0 = nrm.x - 2.f * dot[nl][0];
        float s1 = nrm.y - 2.f * dot[nl][1];
        float s2 = nrm.z - 2.f * dot[nl][2];
        float s3 = nrm.w - 2.f * dot[nl][3];
        unsigned long long key =
            ((unsigned long long)ordbits(s0) << 32) | (unsigned)(tid * 4 + 0);
        unsigned long long k1 =
            ((unsigned long long)ordbits(s1) << 32) | (unsigned)(tid * 4 + 1);
        unsigned long long k2 =
            ((unsigned long long)ordbits(s2) << 32) | (unsigned)(tid * 4 + 2);
        unsigned long long k3 =
            ((unsigned long long)ordbits(s3) << 32) | (unsigned)(tid * 4 + 3);
        if (k1 < key) key = k1;
        if (k2 < key) key = k2;
        if (k3 < key) key = k3;
        for (int off = 32; off; off >>= 1) {
            unsigned long long o = shfl_xor_u64(key, off);
            if (o < key) key = o;
        }
        if (lane == 0) wred[wave][nl] = key;
    }
    __syncthreads();
    if (tid < 16) {
        unsigned long long bkey = wred[0][tid];
        if (wred[1][tid] < bkey) bkey = wred[1][tid];
        if (wred[2][tid] < bkey) bkey = wred[2][tid];
        if (wred[3][tid] < bkey) bkey = wred[3][tid];
        const int code = (int)(bkey & 0xffffffffull);
        codes[(size_t)(n0 + tid) * 8 + iq] = code;
        codes_out[(size_t)(n0 + tid) * 8 + iq] = (float)code;
    }
}

__global__ __launch_bounds__(256)
void rvq_update_k(const float* __restrict__ emb, float* __restrict__ q,
                  const float* __restrict__ cb, const int* __restrict__ codes,
                  float* __restrict__ commit, int iq)
{
    const int n = blockIdx.x, c = threadIdx.x;
    const int code = codes[(size_t)n * 8 + iq];
    const size_t g = (size_t)n * 256 + c;
    const float qv = q[g] + cb[(size_t)code * 256 + c];
    q[g] = qv;
    const float e = qv - emb[g];
    float s = e * e;
    for (int off = 32; off; off >>= 1) s += __shfl_down(s, off, 64);
    __shared__ float ls[4];
    if ((c & 63) == 0) ls[c >> 6] = s;
    __syncthreads();
    if (c == 0) atomicAdd(commit, ls[0] + ls[1] + ls[2] + ls[3]);
}

__global__ void commit_write_k(const float* __restrict__ commit, float* __restrict__ out)
{
    out[0] = commit[0] * (1.f / (4096.f * 256.f));
}

// ============================================================================
extern "C" void kernel_launch(void* const* d_in, const int* in_sizes, int n_in,
                              void* d_out, int out_size, void* d_ws, size_t ws_size,
                              hipStream_t stream)
{
    const float* x    = (const float*)d_in[0];
    const float* ed0w = (const float*)d_in[1];
    const float* ed0b = (const float*)d_in[2];
    const float* edw  = (const float*)d_in[3];
    const float* edb  = (const float*)d_in[4];
    const float* erw  = (const float*)d_in[5];
    const float* erb  = (const float*)d_in[6];
    const float* drw  = (const float*)d_in[7];
    const float* drb  = (const float*)d_in[8];
    const float* duw  = (const float*)d_in[9];
    const float* dub  = (const float*)d_in[10];
    const float* dulw = (const float*)d_in[11];
    const float* dulb = (const float*)d_in[12];
    const float* rsum = (const float*)d_in[13];
    const float* rusg = (const float*)d_in[14];
    float* out = (float*)d_out;

    char* base = (char*)d_ws;
    size_t o = 0;
    ushort_t* wH3 = (ushort_t*)(base + o); o += 31457280;   // 80*3*65536 bf16
    ushort_t* wL3 = (ushort_t*)(base + o); o += 31457280;
    ushort_t* w4H = (ushort_t*)(base + o); o += 4194304;    // 8*4*65536 bf16
    ushort_t* w4L = (ushort_t*)(base + o); o += 4194304;
    ushort_t* AH  = (ushort_t*)(base + o); o += 33554432;   // act [2][32768][256]
    ushort_t* AL  = (ushort_t*)(base + o); o += 33554432;
    ushort_t* BH  = (ushort_t*)(base + o); o += 33554432;
    ushort_t* BL  = (ushort_t*)(base + o); o += 33554432;
    float* emb    = (float*)(base + o);    o += 4194304;
    float* q      = (float*)(base + o);    o += 4194304;
    float* commit = (float*)(base + o);    o += 64;
    float* cb     = (float*)(base + o);    o += 1048576;
    float* cbT    = (float*)(base + o);    o += 1048576;
    float* cbn    = (float*)(base + o);    o += 4096;
    int*   codes  = (int*)(base + o);      o += 131072;

    static const int DIL[4] = {3, 9, 27, 81};

    hipMemsetAsync(q, 0, 4194304 + 64, stream);   // q + commit

    // weight prep
    wprep3_k<<<20480, 256, 0, stream>>>(erw, drw, wH3, wL3);
    wprep4_k<<<2048, 256, 0, stream>>>(edw, duw, w4H, w4L);

    // conv3 dispatch by L (keep >=256 blocks in flight)
    auto conv3 = [&](const ushort_t* iH, const ushort_t* iL,
                     const ushort_t* wh, const ushort_t* wl, const float* bb,
                     const ushort_t* sH, const ushort_t* sL, float alpha,
                     ushort_t* oH, ushort_t* oL, int L, int d) {
        if (L >= 16384)
            convs_k<3, 1, true, 8, 81><<<dim3(L / 128, 1, 2), 256, 0, stream>>>(
                iH, iL, wh, wl, bb, sH, sL, alpha, oH, oL, L, L, d, d);
        else if (L >= 8192)
            convs_k<3, 1, true, 4, 81><<<dim3(L / 64, 1, 2), 256, 0, stream>>>(
                iH, iL, wh, wl, bb, sH, sL, alpha, oH, oL, L, L, d, d);
        else if (L >= 4096)
            convs_k<3, 1, true, 2, 81><<<dim3(L / 32, 1, 2), 256, 0, stream>>>(
                iH, iL, wh, wl, bb, sH, sL, alpha, oH, oL, L, L, d, d);
        else
            convs_k<3, 1, true, 1, 81><<<dim3(L / 16, 1, 2), 256, 0, stream>>>(
                iH, iL, wh, wl, bb, sH, sL, alpha, oH, oL, L, L, d, d);
    };

    // -------------------- encoder --------------------
    down0_k2<<<dim3(32768, 2), 256, 0, stream>>>(x, ed0w, ed0b, AH, AL);
    int L = 32768;
    for (int i = 0; i < 5; ++i) {
        if (i > 0) {
            const ushort_t* wh = w4H + (size_t)(i - 1) * 262144;
            const ushort_t* wl = w4L + (size_t)(i - 1) * 262144;
            const int Lout = L / 2;
            if (Lout >= 16384)
                convs_k<4, 2, false, 8, 1><<<dim3(Lout / 128, 1, 2), 256, 0, stream>>>(
                    AH, AL, wh, wl, edb + (i - 1) * 256, AH, AL, 0.f, BH, BL, L, Lout, 1, 1);
            else if (Lout >= 8192)
                convs_k<4, 2, false, 4, 1><<<dim3(Lout / 64, 1, 2), 256, 0, stream>>>(
                    AH, AL, wh, wl, edb + (i - 1) * 256, AH, AL, 0.f, BH, BL, L, Lout, 1, 1);
            else if (Lout >= 4096)
                convs_k<4, 2, false, 2, 1><<<dim3(Lout / 32, 1, 2), 256, 0, stream>>>(
                    AH, AL, wh, wl, edb + (i - 1) * 256, AH, AL, 0.f, BH, BL, L, Lout, 1, 1);
            else
                convs_k<4, 2, false, 1, 1><<<dim3(Lout / 16, 1, 2), 256, 0, stream>>>(
                    AH, AL, wh, wl, edb + (i - 1) * 256, AH, AL, 0.f, BH, BL, L, Lout, 1, 1);
            ushort_t* t;
            t = AH; AH = BH; BH = t;
            t = AL; AL = BL; BL = t;
            L = Lout;
        }
        for (int j = 0; j < 4; ++j) {
            const int d = DIL[j];
            const size_t u = (size_t)(i * 4 + j) * 2;
            conv3(AH, AL, wH3 + (u + 0) * 196608, wL3 + (u + 0) * 196608,
                  erb + (u + 0) * 256, AH, AL, 0.f, BH, BL, L, d);
            conv3(BH, BL, wH3 + (u + 1) * 196608, wL3 + (u + 1) * 196608,
                  erb + (u + 1) * 256, AH, AL, 1.f, AH, AL, L, 1);
        }
    }

    // -------------------- RVQ --------------------
    emb_k<<<4096, 256, 0, stream>>>(AH, AL, emb);
    for (int iq = 0; iq < 8; ++iq) {
        rvq_cb_k<<<1024, 256, 0, stream>>>(rsum, rusg, cb, cbT, cbn, iq);
        rvq_argmin_k<<<256, 256, 0, stream>>>(emb, q, cbT, cbn, codes, out + 131072, iq);
        rvq_update_k<<<4096, 256, 0, stream>>>(emb, q, cb, codes, commit, iq);
    }
    qsplit_k<<<4096, 256, 0, stream>>>(q, AH, AL);

    // -------------------- decoder --------------------
    L = 2048;
    for (int i = 0; i < 5; ++i) {
        for (int j = 0; j < 4; ++j) {
            const int d = DIL[j];
            const size_t u = 40 + (size_t)(i * 4 + j) * 2;   // decoder slabs 40..79
            conv3(AH, AL, wH3 + (u + 0) * 196608, wL3 + (u + 0) * 196608,
                  drb + ((size_t)(i * 4 + j) * 2 + 0) * 256, AH, AL, 0.f, BH, BL, L, d);
            conv3(BH, BL, wH3 + (u + 1) * 196608, wL3 + (u + 1) * 196608,
                  drb + ((size_t)(i * 4 + j) * 2 + 1) * 256, AH, AL, 2.f, AH, AL, L, 1);
        }
        if (i < 4) {
            const ushort_t* wh = w4H + (size_t)(4 + i) * 262144;
            const ushort_t* wl = w4L + (size_t)(4 + i) * 262144;
            if (L >= 16384)
                convt_k<4><<<dim3(L / 64, 1, 2), 256, 0, stream>>>(
                    AH, AL, wh, wl, dub + i * 256, BH, BL, L);
            else if (L >= 8192)
                convt_k<4><<<dim3(L / 64, 1, 2), 256, 0, stream>>>(
                    AH, AL, wh, wl, dub + i * 256, BH, BL, L);
            else if (L >= 4096)
                convt_k<2><<<dim3(L / 32, 1, 2), 256, 0, stream>>>(
                    AH, AL, wh, wl, dub + i * 256, BH, BL, L);
            else
                convt_k<1><<<dim3(L / 16, 1, 2), 256, 0, stream>>>(
                    AH, AL, wh, wl, dub + i * 256, BH, BL, L);
            ushort_t* t;
            t = AH; AH = BH; BH = t;
            t = AL; AL = BL; BL = t;
            L *= 2;
        } else {
            uplast_k2<<<dim3(L / 256, 2), 256, 0, stream>>>(AH, AL, dulw, dulb, out, L);
        }
    }

    commit_write_k<<<1, 1, 0, stream>>>(commit, out + 163840);
}